// Round 4
// baseline (832.005 us; speedup 1.0000x reference)
//
#include <hip/hip_runtime.h>
#include <hip/hip_bf16.h>

typedef __bf16 bf16_t;
typedef bf16_t bf16x8 __attribute__((ext_vector_type(8)));
typedef bf16_t bf16x4v __attribute__((ext_vector_type(4)));
typedef float f32x4 __attribute__((ext_vector_type(4)));

// async 16B global->LDS (direct, no VGPR round trip)
__device__ __forceinline__ void gll16(const bf16_t* g, bf16_t* l) {
    __builtin_amdgcn_global_load_lds(
        (const __attribute__((address_space(1))) unsigned int*)g,
        (__attribute__((address_space(3))) unsigned int*)l, 16, 0, 0);
}

// ---------------------------------------------------------------------------
// fp32 -> bf16 elementwise (n multiple of 4)
// ---------------------------------------------------------------------------
__global__ __launch_bounds__(256)
void cvt_f32_bf16(const float* __restrict__ in, bf16_t* __restrict__ out, int n4)
{
    int i = blockIdx.x * 256 + threadIdx.x;
    if (i < n4) {
        float4 v = ((const float4*)in)[i];
        bf16x4v o = { (bf16_t)v.x, (bf16_t)v.y, (bf16_t)v.z, (bf16_t)v.w };
        *(bf16x4v*)&out[i * 4] = o;
    }
}

// ---------------------------------------------------------------------------
// Merged fp32->bf16 for 6 weight tensors (fp_w + wq/wk/wv/wo/gat_w), 1 launch.
// ---------------------------------------------------------------------------
__global__ __launch_bounds__(256)
void cvt_multi(const float* __restrict__ fpw, const float* __restrict__ wq,
               const float* __restrict__ wk, const float* __restrict__ wv,
               const float* __restrict__ wo, const float* __restrict__ gw,
               bf16_t* __restrict__ fpwb, bf16_t* __restrict__ wqb,
               bf16_t* __restrict__ wkb, bf16_t* __restrict__ wvb,
               bf16_t* __restrict__ wob, bf16_t* __restrict__ gwb)
{
    int id = blockIdx.x * 256 + threadIdx.x;    // < 2621440
    const float* src; bf16_t* dst; int off;
    if (id < 1310720) { src = fpw; dst = fpwb; off = id; }
    else {
        int id3 = id - 1310720;
        int w = id3 >> 18; off = id3 & 262143;
        const float* ss[5] = {wq, wk, wv, wo, gw};
        bf16_t* dd[5] = {wqb, wkb, wvb, wob, gwb};
        src = ss[w]; dst = dd[w];
    }
    float4 v = ((const float4*)src)[off];
    bf16x4v o = { (bf16_t)v.x, (bf16_t)v.y, (bf16_t)v.z, (bf16_t)v.w };
    *(bf16x4v*)&dst[off * 4] = o;
}

// ---------------------------------------------------------------------------
// Reorder conv weights (O,C,7) fp32 -> bf16 planes [(i*7+kk)][o][c].
// Thread handles 4 consecutive c for one (i,o,kk): 4 scalar loads (stride 28B)
// + one 8B store (fully coalesced 512B/wave).
// ---------------------------------------------------------------------------
__global__ __launch_bounds__(256)
void reorder_convw(const float* w0, const float* w1, const float* w2,
                   const float* w3, const float* w4, bf16_t* __restrict__ out)
{
    int gid = blockIdx.x * 256 + threadIdx.x;       // < 5*1024*7*256 = 9175040
    int i = gid / 1835008;
    int w = gid - i * 1835008;
    int o = w / 1792;
    int r2 = w - o * 1792;
    int kk = r2 >> 8, c4 = (r2 & 255) * 4;
    const float* ws[5] = {w0, w1, w2, w3, w4};
    const float* src = ws[i] + (size_t)o * 7168 + c4 * 7 + kk;
    bf16x4v v = { (bf16_t)src[0], (bf16_t)src[7], (bf16_t)src[14], (bf16_t)src[21] };
    *(bf16x4v*)&out[((size_t)(i * 7 + kk) << 20) + (o << 10) + c4] = v;
}

// conv biases -> cball[5120]; bq||bk -> qkbias[2048]; zero page init
__global__ __launch_bounds__(256)
void gather_bias(const float* b0, const float* b1, const float* b2,
                 const float* b3, const float* b4,
                 const float* bq, const float* bk,
                 float* __restrict__ out, float* __restrict__ qkbias,
                 bf16_t* __restrict__ zp)
{
    int idx = blockIdx.x * 256 + threadIdx.x;       // grid 28 -> 7168
    if (blockIdx.x == 0 && threadIdx.x < 32) zp[threadIdx.x] = (bf16_t)0.0f;
    if (idx < 5120) {
        const float* bs[5] = {b0, b1, b2, b3, b4};
        out[idx] = bs[idx >> 10][idx & 1023];
    } else {
        int j = idx - 5120;                          // < 2048
        qkbias[j] = (j < 1024) ? bq[j] : bk[j - 1024];
    }
}

// ---------------------------------------------------------------------------
// bf16 MFMA NT GEMM: out[n, m] = sum_k A[n,k]*B[m,k] + bias[...]
// Tile NRx128 (NR in {128,64}), BK=32, 4 waves, 16x16x32 MFMA.
//
// Depth-3 pipelined staging, 4 LDS buffers, counted vmcnt (8/4/0 for NR=128,
// 6/3/0 for NR=64).  Per K-step: wait(tile s) -> barrier -> sched_barrier ->
// ds_read frags(s) -> issue stage(s+3) -> MFMA.  ~750 cyc of load slack.
//
// LDS slot swizzle: 16B slot ^= (row>>1)&3 on the global source column and
// the ds_read slot -> conflict-free ds_read_b128.
//
// Conv A staging has a wave-uniform slab fast path: a 16-row slab can only
// go OOB within |shift| rows of a 256 boundary; test once per slab (scalar
// branch), branchless address otherwise.
//
// BIAS_ROW: bias indexed by n (row) instead of oc0+m (transposed-out GEMM).
// ---------------------------------------------------------------------------
template<bool CONV, bool OUT_BF16, bool BIAS_ROW = false, int NR = 128>
__global__ __launch_bounds__(256)
void mfma_gemm(const bf16_t* __restrict__ A, const bf16_t* __restrict__ Bw,
               const float* __restrict__ bias, void* __restrict__ outv,
               const bf16_t* __restrict__ zp,
               int Kd, int lda, int ldb, int ldo, int out_col0)
{
    constexpr int FN = NR / 32;                  // 4 (NR=128) or 2 (NR=64)
    __shared__ __align__(16) bf16_t As[4][NR * 32];
    __shared__ __align__(16) bf16_t Bs[4][128 * 32];
    const int t = threadIdx.x;
    const int lane = t & 63, wave = t >> 6;
    const int wn = (wave & 1) * (NR / 2), wm = (wave >> 1) * 64;
    const int q = lane >> 4, lr = lane & 15;
    const int mt = CONV ? (blockIdx.x & 7) : blockIdx.x;
    const int conv_i = CONV ? (blockIdx.x >> 3) : 0;
    const int m0 = mt * 128, n0 = blockIdx.y * NR;
    const int srow = lane >> 2, sseg = lane & 3;           // staging row/16B-seg
    const int sw_seg = sseg ^ ((srow >> 1) & 3);           // swizzled source seg
    const int slotq = (q ^ ((lr >> 1) & 3)) * 8;           // swizzled read slot

    f32x4 acc[FN][4];
    #pragma unroll
    for (int a = 0; a < FN; a++)
        #pragma unroll
        for (int b = 0; b < 4; b++) acc[a][b] = (f32x4){0.f, 0.f, 0.f, 0.f};

    const int ksteps = Kd >> 5;
    const int T = CONV ? ksteps * 7 : ksteps;

    // stage cursor (advanced once per stage call, in issue order)
    int s_tap = 0, s_k0 = 0;
    auto do_stage = [&](int bi) {
        const bf16_t* Bp = CONV ? (Bw + ((size_t)(conv_i * 7 + s_tap) << 20)) : Bw;
        const int shift = CONV ? ((s_tap - 3) << conv_i) : 0;
        #pragma unroll
        for (int p = 0; p < NR / 64; p++) {
            const int slab = p * 64 + wave * 16;   // 16-row slab base
            const bf16_t* ga;
            if (CONV) {
                const int slabN = n0 + slab;               // wave-uniform
                const int inSeg = slabN & 255;             // wave-uniform
                if (inSeg + shift >= 0 && inSeg + shift <= 240) {
                    // whole slab in-bounds: branchless address
                    ga = A + (size_t)(slabN + srow + shift) * lda + s_k0 + sw_seg * 8;
                } else {
                    int n = slabN + srow;
                    int tg = (n & 255) + shift;
                    ga = ((unsigned)tg < 256u)
                       ? A + (size_t)((n & ~255) + tg) * lda + s_k0 + sw_seg * 8
                       : zp + sseg * 8;
                }
            } else {
                ga = A + (size_t)(n0 + slab + srow) * lda + s_k0 + sw_seg * 8;
            }
            gll16(ga, &As[bi][slab * 32]);
        }
        #pragma unroll
        for (int p = 0; p < 2; p++) {
            const int slab = p * 64 + wave * 16;
            const int rr = slab + srow;
            gll16(Bp + (size_t)(m0 + rr) * ldb + s_k0 + sw_seg * 8, &Bs[bi][slab * 32]);
        }
        s_k0 += 32;
        if (CONV && s_k0 == Kd) { s_k0 = 0; s_tap++; }
    };

    // prologue: 3 tiles in flight
    do_stage(0);
    do_stage(1);
    do_stage(2);

    int cur = 0;
    for (int s = 0; s < T; s++) {
        if (s + 2 < T) {
            if constexpr (NR == 128) asm volatile("s_waitcnt vmcnt(8)" ::: "memory");
            else                     asm volatile("s_waitcnt vmcnt(6)" ::: "memory");
        } else if (s + 1 < T) {
            if constexpr (NR == 128) asm volatile("s_waitcnt vmcnt(4)" ::: "memory");
            else                     asm volatile("s_waitcnt vmcnt(3)" ::: "memory");
        } else {
            asm volatile("s_waitcnt vmcnt(0)" ::: "memory");
        }
        __builtin_amdgcn_s_barrier();
        __builtin_amdgcn_sched_barrier(0);

        // fragments first -- lgkm wait overlaps the stage issue below
        bf16x8 af[FN], bfv[4];
        #pragma unroll
        for (int f = 0; f < FN; f++)
            af[f] = *(bf16x8*)&As[cur][(wn + f * 16 + lr) * 32 + slotq];
        #pragma unroll
        for (int f = 0; f < 4; f++)
            bfv[f] = *(bf16x8*)&Bs[cur][(wm + f * 16 + lr) * 32 + slotq];

        int nb = (cur + 3) & 3;
        if (s + 3 < T) do_stage(nb);

        __builtin_amdgcn_s_setprio(1);
        #pragma unroll
        for (int fn = 0; fn < FN; fn++)
            #pragma unroll
            for (int fm = 0; fm < 4; fm++)
                acc[fn][fm] = __builtin_amdgcn_mfma_f32_16x16x32_bf16(
                    af[fn], bfv[fm], acc[fn][fm], 0, 0, 0);
        __builtin_amdgcn_s_setprio(0);
        cur = (cur + 1) & 3;
    }

    const int oc0 = CONV ? (conv_i << 10) : out_col0;
    #pragma unroll
    for (int fn = 0; fn < FN; fn++) {
        #pragma unroll
        for (int r = 0; r < 4; r++) {
            int n = n0 + wn + fn * 16 + q * 4 + r;
            #pragma unroll
            for (int fm = 0; fm < 4; fm++) {
                int m = m0 + wm + fm * 16 + lr;
                float v = acc[fn][fm][r];
                if (bias) v += bias[BIAS_ROW ? n : (oc0 + m)];
                if (OUT_BF16)
                    ((bf16_t*)outv)[(size_t)n * ldo + oc0 + m] = (bf16_t)v;
                else
                    ((float*)outv)[(size_t)n * ldo + oc0 + m] = v;
            }
        }
    }
}

// ---------------------------------------------------------------------------
// LayerNorm (eps 1e-5) + exact GELU, in place on z (fp32) + bf16 copy zb.
// ---------------------------------------------------------------------------
__global__ __launch_bounds__(256)
void ln_gelu(float* __restrict__ z, bf16_t* __restrict__ zb,
             const float* __restrict__ g, const float* __restrict__ b)
{
    __shared__ float r1[256], r2[256];
    const int n = blockIdx.x, t = threadIdx.x;
    float* row = z + (size_t)n * 1024;
    float x[4], s = 0.f, s2 = 0.f;
    #pragma unroll
    for (int u = 0; u < 4; u++) {
        x[u] = row[t + u * 256];
        s += x[u]; s2 += x[u] * x[u];
    }
    r1[t] = s; r2[t] = s2;
    __syncthreads();
    for (int off = 128; off > 0; off >>= 1) {
        if (t < off) { r1[t] += r1[t + off]; r2[t] += r2[t + off]; }
        __syncthreads();
    }
    const float mu  = r1[0] * (1.0f / 1024.0f);
    const float var = r2[0] * (1.0f / 1024.0f) - mu * mu;
    const float rstd = rsqrtf(var + 1e-5f);
    #pragma unroll
    for (int u = 0; u < 4; u++) {
        int c = t + u * 256;
        float y = (x[u] - mu) * rstd * g[c] + b[c];
        float gv = 0.5f * y * (1.0f + erff(y * 0.70710678118654752f));
        row[c] = gv;
        zb[(size_t)n * 1024 + c] = (bf16_t)gv;
    }
}

// ---------------------------------------------------------------------------
// MFMA flash attention.
// Grid (2 i-tiles x 16 heads x 8 batch) = 256 blocks, 4 waves.
// q,k: interleaved QK buffer [2048][2048] bf16 (cols 0-1023 = Q, 1024-2047 = K);
// vt: [1024 dims][2048 tokens] bf16.  ctx: [2048][1024].
// LDS XOR-swizzled (16B slot ^= row&7).
// ---------------------------------------------------------------------------
__global__ __launch_bounds__(256)
void attn_mfma(const bf16_t* __restrict__ qg, const bf16_t* __restrict__ kg,
               const bf16_t* __restrict__ vt, bf16_t* __restrict__ ctx)
{
    const int it = blockIdx.x, h = blockIdx.y, bb = blockIdx.z;
    const int t = threadIdx.x, lane = t & 63, wave = t >> 6;
    const int q4 = lane >> 4, lr = lane & 15;
    const size_t qkbase = (size_t)bb * 256 * 2048 + (size_t)h * 64;

    __shared__ __align__(16) bf16_t Qs[4][32 * 64];   // per-wave Q rows
    __shared__ __align__(16) bf16_t Ks[64 * 64];      // K chunk  [j][d]
    __shared__ __align__(16) bf16_t Vs[64 * 64];      // Vt chunk [d][j]
    __shared__ __align__(16) bf16_t Ps[4][32 * 64];   // per-wave P tile [i][j]

    // ---- stage Q (128 rows x 64, swizzled), cooperative ----
    {
        const int itbase = it * 128;
        #pragma unroll
        for (int rep = 0; rep < 4; rep++) {
            int idx = rep * 256 + t;
            int rl = idx >> 3, seg = idx & 7;
            bf16x8 v = *(const bf16x8*)&qg[qkbase + (size_t)(itbase + rl) * 2048 + seg * 8];
            *(bf16x8*)&Qs[rl >> 5][(rl & 31) * 64 + ((seg ^ (rl & 7)) << 3)] = v;
        }
    }

    f32x4 o[2][4];                 // O accum: [fn rows][fd d-frag]
    float mrow[2][4], lrow[2][4];  // online softmax state per (fn, r)
    #pragma unroll
    for (int fn = 0; fn < 2; fn++)
        #pragma unroll
        for (int x = 0; x < 4; x++) {
            o[fn][x] = (f32x4){0.f, 0.f, 0.f, 0.f};
            mrow[fn][x] = -1e30f; lrow[fn][x] = 0.f;
        }

    for (int j0 = 0; j0 < 256; j0 += 64) {
        __syncthreads();           // prev chunk's K/V reads done (also covers Q stage)
        // ---- stage K chunk [64 j][64 d] and Vt chunk [64 d][64 j], swizzled ----
        #pragma unroll
        for (int rep = 0; rep < 2; rep++) {
            int idx = rep * 256 + t;
            int rl = idx >> 3, seg = idx & 7;
            bf16x8 kv = *(const bf16x8*)&kg[qkbase + (size_t)(j0 + rl) * 2048 + seg * 8];
            *(bf16x8*)&Ks[rl * 64 + ((seg ^ (rl & 7)) << 3)] = kv;
            bf16x8 vv = *(const bf16x8*)&vt[(size_t)(h * 64 + rl) * 2048 + bb * 256 + j0 + seg * 8];
            *(bf16x8*)&Vs[rl * 64 + ((seg ^ (rl & 7)) << 3)] = vv;
        }
        __syncthreads();

        // ---- S = Q K^T  (wave's 32 rows x 64 j) ----
        f32x4 s[2][4];
        #pragma unroll
        for (int fn = 0; fn < 2; fn++)
            #pragma unroll
            for (int fm = 0; fm < 4; fm++) s[fn][fm] = (f32x4){0.f, 0.f, 0.f, 0.f};
        #pragma unroll
        for (int kk = 0; kk < 2; kk++) {
            bf16x8 aq[2], bk[4];
            #pragma unroll
            for (int fn = 0; fn < 2; fn++) {
                int row = fn * 16 + lr;
                aq[fn] = *(bf16x8*)&Qs[wave][row * 64 + (((kk * 4 + q4) ^ (row & 7)) << 3)];
            }
            #pragma unroll
            for (int fm = 0; fm < 4; fm++) {
                int row = fm * 16 + lr;
                bk[fm] = *(bf16x8*)&Ks[row * 64 + (((kk * 4 + q4) ^ (row & 7)) << 3)];
            }
            #pragma unroll
            for (int fn = 0; fn < 2; fn++)
                #pragma unroll
                for (int fm = 0; fm < 4; fm++)
                    s[fn][fm] = __builtin_amdgcn_mfma_f32_16x16x32_bf16(
                        aq[fn], bk[fm], s[fn][fm], 0, 0, 0);
        }

        // ---- online softmax update + P (bf16) into wave-private LDS ----
        #pragma unroll
        for (int fn = 0; fn < 2; fn++) {
            #pragma unroll
            for (int r = 0; r < 4; r++) {
                float sv[4];
                #pragma unroll
                for (int fm = 0; fm < 4; fm++) sv[fm] = s[fn][fm][r] * 0.125f;
                float rm = fmaxf(fmaxf(sv[0], sv[1]), fmaxf(sv[2], sv[3]));
                rm = fmaxf(rm, __shfl_xor(rm, 1));
                rm = fmaxf(rm, __shfl_xor(rm, 2));
                rm = fmaxf(rm, __shfl_xor(rm, 4));
                rm = fmaxf(rm, __shfl_xor(rm, 8));
                float mold = mrow[fn][r];
                float mnew = fmaxf(mold, rm);
                float scl = __expf(mold - mnew);
                mrow[fn][r] = mnew;
                int prow = fn * 16 + q4 * 4 + r;
                float psum = 0.f;
                #pragma unroll
                for (int fm = 0; fm < 4; fm++) {
                    float p = __expf(sv[fm] - mnew);
                    psum += p;
                    int col = fm * 16 + lr;
                    Ps[wave][prow * 64 + (col ^ ((prow & 7) << 3))] = (bf16_t)p;
                }
                psum += __shfl_xor(psum, 1);
                psum += __shfl_xor(psum, 2);
                psum += __shfl_xor(psum, 4);
                psum += __shfl_xor(psum, 8);
                lrow[fn][r] = lrow[fn][r] * scl + psum;
                #pragma unroll
                for (int fd = 0; fd < 4; fd++) o[fn][fd][r] *= scl;
            }
        }

        // ---- O += P V  (wave-private Ps: in-order same-wave DS, no barrier) ----
        #pragma unroll
        for (int kk = 0; kk < 2; kk++) {
            bf16x8 ap[2], bvf[4];
            #pragma unroll
            for (int fn = 0; fn < 2; fn++) {
                int row = fn * 16 + lr;
                ap[fn] = *(bf16x8*)&Ps[wave][row * 64 + (((kk * 4 + q4) ^ (row & 7)) << 3)];
            }
            #pragma unroll
            for (int fd = 0; fd < 4; fd++) {
                int row = fd * 16 + lr;
                bvf[fd] = *(bf16x8*)&Vs[row * 64 + (((kk * 4 + q4) ^ (row & 7)) << 3)];
            }
            #pragma unroll
            for (int fn = 0; fn < 2; fn++)
                #pragma unroll
                for (int fd = 0; fd < 4; fd++)
                    o[fn][fd] = __builtin_amdgcn_mfma_f32_16x16x32_bf16(
                        ap[fn], bvf[fd], o[fn][fd], 0, 0, 0);
        }
    }

    // ---- epilogue: normalize, write ctx ----
    const int i0 = it * 128 + wave * 32;
    #pragma unroll
    for (int fn = 0; fn < 2; fn++) {
        #pragma unroll
        for (int r = 0; r < 4; r++) {
            float inv = 1.0f / lrow[fn][r];
            int row = i0 + fn * 16 + q4 * 4 + r;
            #pragma unroll
            for (int fd = 0; fd < 4; fd++) {
                int col = h * 64 + fd * 16 + lr;
                ctx[(size_t)bb * 262144 + (size_t)row * 1024 + col] =
                    (bf16_t)(o[fn][fd][r] * inv);
            }
        }
    }
}

// ---------------------------------------------------------------------------
// GAT logits, TRANSPOSED out: e1t[h][n] = hg[n,h,:].a1 ; e2t likewise.
// ---------------------------------------------------------------------------
__global__ __launch_bounds__(256)
void gat_e(const float* __restrict__ hg, const float* __restrict__ a1,
           const float* __restrict__ a2, float* __restrict__ e1t,
           float* __restrict__ e2t)
{
    int id = blockIdx.x * 256 + threadIdx.x;  // < 16384
    int h = id >> 11, n = id & 2047;
    const float* hr = hg + (size_t)n * 1024 + h * 128;
    float s1 = 0.f, s2 = 0.f;
    for (int d = 0; d < 128; d += 4) {
        float4 x = *(const float4*)&hr[d];
        float4 u1 = *(const float4*)&a1[d];
        float4 u2 = *(const float4*)&a2[d];
        s1 += x.x * u1.x + x.y * u1.y + x.z * u1.z + x.w * u1.w;
        s2 += x.x * u2.x + x.y * u2.y + x.z * u2.z + x.w * u2.w;
    }
    e1t[id] = s1; e2t[id] = s2;
}

// ---------------------------------------------------------------------------
// Transpose hg (2048 x 1024, fp32) -> hgT (1024 x 2048, bf16), 32x32 tiles.
// ---------------------------------------------------------------------------
__global__ __launch_bounds__(256)
void transpose_hg(const float* __restrict__ in, bf16_t* __restrict__ out)
{
    __shared__ float tile[32][33];
    const int t = threadIdx.x;
    const int j0 = blockIdx.x * 32, c0 = blockIdx.y * 32;
    {
        int jl = t >> 3, cl = (t & 7) * 4;
        float4 v = *(const float4*)(in + (size_t)(j0 + jl) * 1024 + c0 + cl);
        tile[jl][cl] = v.x; tile[jl][cl + 1] = v.y;
        tile[jl][cl + 2] = v.z; tile[jl][cl + 3] = v.w;
    }
    __syncthreads();
    {
        int cl = t >> 3, jl = (t & 7) * 4;
        bf16x4v o = { (bf16_t)tile[jl][cl], (bf16_t)tile[jl + 1][cl],
                      (bf16_t)tile[jl + 2][cl], (bf16_t)tile[jl + 3][cl] };
        *(bf16x4v*)&out[(size_t)(c0 + cl) * 2048 + j0 + jl] = o;
    }
}

// ---------------------------------------------------------------------------
// Fused GAT softmax-aggregate via MFMA.  Grid (32, 8) x 256.
// Exact row max without a scan pass: leaky_relu is monotone, so
// m_i = leaky(e1_i + max_j e2_j); the denominator is accumulated as per-thread
// register partial sums inside the P-build loop (thread->(i,jg) mapping is
// j0-invariant) and reduced with 16-lane shuffles at the end.
// ---------------------------------------------------------------------------
__global__ __launch_bounds__(256)
void gat_agg_mfma(const bf16_t* __restrict__ hgT, const float* __restrict__ e1t,
                  const float* __restrict__ e2t, const float* __restrict__ feat,
                  float* __restrict__ outp)
{
    const int it = blockIdx.x, h = blockIdx.y;
    const int i0 = it * 64;
    __shared__ float e2s[2048];
    __shared__ float e1s[64], mS[64], lSinv[64];
    __shared__ float wmax[4];
    __shared__ __align__(16) bf16_t Ps[64 * 136];
    __shared__ __align__(16) bf16_t Hs[128 * 136];
    const int t = threadIdx.x;
    const int lane = t & 63, wave = t >> 6;
    const int q = lane >> 4, lr = lane & 15;
    const int wm = wave * 32;

    // stage e2 row + block-wide max(e2)
    float lmax = -1e30f;
    for (int idx = t; idx < 2048; idx += 256) {
        float v = e2t[h * 2048 + idx];
        e2s[idx] = v;
        lmax = fmaxf(lmax, v);
    }
    if (t < 64) e1s[t] = e1t[h * 2048 + i0 + t];
    #pragma unroll
    for (int d = 1; d < 64; d <<= 1) lmax = fmaxf(lmax, __shfl_xor(lmax, d));
    if (lane == 0) wmax[wave] = lmax;
    __syncthreads();
    {
        float maxE2 = fmaxf(fmaxf(wmax[0], wmax[1]), fmaxf(wmax[2], wmax[3]));
        if (t < 64) {
            float x = e1s[t] + maxE2;
            mS[t] = (x >= 0.f) ? x : 0.2f * x;     // exact row max of leaky(e1+e2)
        }
    }
    __syncthreads();

    f32x4 acc[4][2];
    #pragma unroll
    for (int a = 0; a < 4; a++)
        #pragma unroll
        for (int b = 0; b < 2; b++) acc[a][b] = (f32x4){0.f, 0.f, 0.f, 0.f};
    float psum[4] = {0.f, 0.f, 0.f, 0.f};          // per-(i,jg) denom partials

    for (int j0 = 0; j0 < 2048; j0 += 128) {
        for (int idx = t; idx < 2048; idx += 256) {
            int d = idx >> 4, seg = idx & 15;
            *(bf16x8*)&Hs[d * 136 + seg * 8] =
                *(const bf16x8*)&hgT[(size_t)(h * 128 + d) * 2048 + j0 + seg * 8];
        }
        #pragma unroll
        for (int rep = 0; rep < 4; rep++) {
            int idx = rep * 256 + t;
            int i = idx >> 4, jg = idx & 15;
            float ei = e1s[i], mi = mS[i];
            bf16x8 pv;
            #pragma unroll
            for (int u = 0; u < 8; u++) {
                float x = ei + e2s[j0 + jg * 8 + u];
                x = (x >= 0.f) ? x : 0.2f * x;
                float p = __expf(x - mi);
                psum[rep] += p;
                pv[u] = (bf16_t)p;
            }
            *(bf16x8*)&Ps[i * 136 + jg * 8] = pv;
        }
        __syncthreads();
        #pragma unroll
        for (int kb = 0; kb < 4; kb++) {
            bf16x8 af[4], bf2[2];
            #pragma unroll
            for (int fn = 0; fn < 4; fn++)
                af[fn] = *(bf16x8*)&Ps[(fn * 16 + lr) * 136 + kb * 32 + q * 8];
            #pragma unroll
            for (int fm = 0; fm < 2; fm++)
                bf2[fm] = *(bf16x8*)&Hs[(wm + fm * 16 + lr) * 136 + kb * 32 + q * 8];
            #pragma unroll
            for (int fn = 0; fn < 4; fn++)
                #pragma unroll
                for (int fm = 0; fm < 2; fm++)
                    acc[fn][fm] = __builtin_amdgcn_mfma_f32_16x16x32_bf16(
                        af[fn], bf2[fm], acc[fn][fm], 0, 0, 0);
        }
        __syncthreads();
    }

    // reduce denom partials: 16 consecutive threads share a row
    #pragma unroll
    for (int rep = 0; rep < 4; rep++) {
        float v = psum[rep];
        v += __shfl_xor(v, 1);
        v += __shfl_xor(v, 2);
        v += __shfl_xor(v, 4);
        v += __shfl_xor(v, 8);
        if ((t & 15) == 0) lSinv[rep * 16 + (t >> 4)] = 1.0f / v;
    }
    __syncthreads();

    #pragma unroll
    for (int fn = 0; fn < 4; fn++) {
        #pragma unroll
        for (int r = 0; r < 4; r++) {
            int il = fn * 16 + q * 4 + r;
            int i = i0 + il;
            float inv = lSinv[il];
            #pragma unroll
            for (int fm = 0; fm < 2; fm++) {
                int col = h * 128 + wm + fm * 16 + lr;
                float v = acc[fn][fm][r] * inv;
                v = (v > 0.f) ? v : (expf(v) - 1.0f);
                size_t off = (size_t)i * 1024 + col;
                outp[off] = v + feat[off];
            }
        }
    }
}

// ---------------------------------------------------------------------------
extern "C" void kernel_launch(void* const* d_in, const int* in_sizes, int n_in,
                              void* d_out, int out_size, void* d_ws, size_t ws_size,
                              hipStream_t stream)
{
    const float* feat = (const float*)d_in[0];
    const float *cw[5], *cb[5];
    if (in_sizes[2] == 1024) {
        for (int i = 0; i < 5; i++) { cw[i] = (const float*)d_in[1 + 2*i]; cb[i] = (const float*)d_in[2 + 2*i]; }
    } else {
        for (int i = 0; i < 5; i++) { cw[i] = (const float*)d_in[1 + i];   cb[i] = (const float*)d_in[6 + i]; }
    }
    const float* fp_w = (const float*)d_in[11];
    const float* fp_b = (const float*)d_in[12];
    const float* ln_g = (const float*)d_in[13];
    const float* ln_b = (const float*)d_in[14];
    const float* wq = (const float*)d_in[15]; const float* bq = (const float*)d_in[16];
    const float* wk = (const float*)d_in[17]; const float* bk = (const float*)d_in[18];
    const float* wv = (const float*)d_in[19]; const float* bv = (const float*)d_in[20];
    const float* wo = (const float*)d_in[21]; const float* bo = (const float*)d_in[22];
    const float* gat_w = (const float*)d_in[23]; const float* gat_b = (const float*)d_in[24];
    const float* ga1 = (const float*)d_in[25]; const float* ga2 = (const float*)d_in[26];
    float* outp = (float*)d_out;

    // ---- workspace layout (~118 MiB) ----
    char* wsb = (char*)d_ws;
    bf16_t* xb    = (bf16_t*)(wsb);                     //  4,194,304
    bf16_t* msb   = (bf16_t*)(wsb + 4194304);           // 20,971,520
    bf16_t* wcb   = (bf16_t*)(wsb + 25165824);          // 73,400,320
    float*  zf    = (float*) (wsb + 98566144);          //  8,388,608
    bf16_t* zb    = (bf16_t*)(wsb + 106954752);         //  4,194,304
    bf16_t* qb    = (bf16_t*)(wsb + 111149056);         //  4,194,304
    bf16_t* kb    = (bf16_t*)(wsb + 115343360);         //  4,194,304
    bf16_t* vb    = (bf16_t*)(wsb + 119537664);         //  4,194,304 (Vt [1024][2048])
    float*  cball = (float*) (wsb + 123731968);         //     20,480
    float*  e1t   = (float*) (wsb + 123752448);         //     65,536
    float*  e2t   = (float*) (wsb + 123817984);         //     65,536
    bf16_t* zpage = (bf16_t*)(wsb + 123883520);         //         64
    // aliases (stream-ordered reuse):
    bf16_t* fpwb = wcb;                 // wcb dead after conv GEMM
    bf16_t* wqb  = wcb + 5242880;       // wq||wk contiguous for merged QK GEMM
    bf16_t* wkb  = wqb + 1048576;
    bf16_t* wvb  = wkb + 1048576;
    bf16_t* wob  = wvb + 1048576;
    bf16_t* gwb  = wob + 1048576;
    bf16_t* qkb  = qb;                  // merged QK output [2048][2048] (qb+kb)
    float*  qkbias = e1t;               // e1t not needed until step 10
    bf16_t* ctxb = zb;                  // zb dead after QK/V projections
    bf16_t* attb = kb;                  // qkb dead after attn
    float*  hgb  = zf;                  // zf dead after ln_gelu
    bf16_t* hgtb = msb;                 // msb dead after fusion GEMM

    const dim3 blk(256);

    // 1) feat conversion + conv weight reorder + bias gathers + zero page
    cvt_f32_bf16<<<dim3(2048), blk, 0, stream>>>(feat, xb, 524288);
    reorder_convw<<<dim3(35840), blk, 0, stream>>>(cw[0], cw[1], cw[2], cw[3], cw[4], wcb);
    gather_bias<<<dim3(28), blk, 0, stream>>>(cb[0], cb[1], cb[2], cb[3], cb[4],
                                              bq, bk, cball, qkbias, zpage);

    // 2) all 5 dilated convs, one MFMA launch -> msb (bf16, ld 5120)
    mfma_gemm<true, true><<<dim3(40, 16), blk, 0, stream>>>(
        xb, wcb, cball, msb, zpage, 1024, 1024, 1024, 5120, 0);

    // 3) remaining weight conversions (single launch; aliases wcb, so after conv)
    cvt_multi<<<dim3(10240), blk, 0, stream>>>(fp_w, wq, wk, wv, wo, gat_w,
                                               fpwb, wqb, wkb, wvb, wob, gwb);

    // 4) fusion projection -> zf (fp32); 64-row tiles -> 256 blocks
    mfma_gemm<false, false, false, 64><<<dim3(8, 32), blk, 0, stream>>>(
        msb, fpwb, fp_b, zf, zpage, 5120, 5120, 5120, 1024, 0);

    // 5) LN + GELU -> zf (fp32) and zb (bf16)
    ln_gelu<<<dim3(2048), blk, 0, stream>>>(zf, zb, ln_g, ln_b);

    // 6) merged Q+K projection -> qkb [2048][2048]; V operand-swapped -> Vt
    mfma_gemm<false, true><<<dim3(16, 16), blk, 0, stream>>>(
        zb, wqb, qkbias, qkb, zpage, 1024, 1024, 1024, 2048, 0);
    mfma_gemm<false, true, true, 64><<<dim3(16, 16), blk, 0, stream>>>(
        wvb, zb, bv, vb, zpage, 1024, 1024, 1024, 2048, 0);

    // 7) MFMA flash attention -> ctxb (bf16)
    attn_mfma<<<dim3(2, 16, 8), blk, 0, stream>>>(qkb, qkb + 1024, vb, ctxb);

    // 8) output projection -> attb (bf16); 64-row tiles
    mfma_gemm<false, true, false, 64><<<dim3(8, 32), blk, 0, stream>>>(
        ctxb, wob, bo, attb, zpage, 1024, 1024, 1024, 1024, 0);

    // 9) GAT projection -> hgb (fp32); 64-row tiles
    mfma_gemm<false, false, false, 64><<<dim3(8, 32), blk, 0, stream>>>(
        attb, gwb, gat_b, hgb, zpage, 1024, 1024, 1024, 1024, 0);

    // 10) GAT: transpose hg, logits, fused softmax-aggregate (MFMA)
    transpose_hg<<<dim3(64, 32), blk, 0, stream>>>(hgb, hgtb);
    gat_e<<<dim3(64), blk, 0, stream>>>(hgb, ga1, ga2, e1t, e2t);
    gat_agg_mfma<<<dim3(32, 8), blk, 0, stream>>>(hgtb, e1t, e2t, feat, outp);
}

// Round 5
// 752.071 us; speedup vs baseline: 1.1063x; 1.1063x over previous
//
#include <hip/hip_runtime.h>
#include <hip/hip_bf16.h>

typedef __bf16 bf16_t;
typedef bf16_t bf16x8 __attribute__((ext_vector_type(8)));
typedef bf16_t bf16x4v __attribute__((ext_vector_type(4)));
typedef float f32x4 __attribute__((ext_vector_type(4)));

// async 16B global->LDS (direct, no VGPR round trip)
__device__ __forceinline__ void gll16(const bf16_t* g, bf16_t* l) {
    __builtin_amdgcn_global_load_lds(
        (const __attribute__((address_space(1))) unsigned int*)g,
        (__attribute__((address_space(3))) unsigned int*)l, 16, 0, 0);
}

// ---------------------------------------------------------------------------
// fp32 -> bf16 elementwise (n multiple of 4)
// ---------------------------------------------------------------------------
__global__ __launch_bounds__(256)
void cvt_f32_bf16(const float* __restrict__ in, bf16_t* __restrict__ out, int n4)
{
    int i = blockIdx.x * 256 + threadIdx.x;
    if (i < n4) {
        float4 v = ((const float4*)in)[i];
        bf16x4v o = { (bf16_t)v.x, (bf16_t)v.y, (bf16_t)v.z, (bf16_t)v.w };
        *(bf16x4v*)&out[i * 4] = o;
    }
}

// ---------------------------------------------------------------------------
// Merged fp32->bf16 for 6 weight tensors (fp_w + wq/wk/wv/wo/gat_w), 1 launch.
// ---------------------------------------------------------------------------
__global__ __launch_bounds__(256)
void cvt_multi(const float* __restrict__ fpw, const float* __restrict__ wq,
               const float* __restrict__ wk, const float* __restrict__ wv,
               const float* __restrict__ wo, const float* __restrict__ gw,
               bf16_t* __restrict__ fpwb, bf16_t* __restrict__ wqb,
               bf16_t* __restrict__ wkb, bf16_t* __restrict__ wvb,
               bf16_t* __restrict__ wob, bf16_t* __restrict__ gwb)
{
    int id = blockIdx.x * 256 + threadIdx.x;    // < 2621440
    const float* src; bf16_t* dst; int off;
    if (id < 1310720) { src = fpw; dst = fpwb; off = id; }
    else {
        int id3 = id - 1310720;
        int w = id3 >> 18; off = id3 & 262143;
        const float* ss[5] = {wq, wk, wv, wo, gw};
        bf16_t* dd[5] = {wqb, wkb, wvb, wob, gwb};
        src = ss[w]; dst = dd[w];
    }
    float4 v = ((const float4*)src)[off];
    bf16x4v o = { (bf16_t)v.x, (bf16_t)v.y, (bf16_t)v.z, (bf16_t)v.w };
    *(bf16x4v*)&dst[off * 4] = o;
}

// ---------------------------------------------------------------------------
// Reorder conv weights (O,C,7) fp32 -> bf16 planes [(i*7+kk)][o][c].
// Thread handles 4 consecutive c for one (i,o,kk): 4 scalar loads (stride 28B)
// + one 8B store (fully coalesced 512B/wave).
// ---------------------------------------------------------------------------
__global__ __launch_bounds__(256)
void reorder_convw(const float* w0, const float* w1, const float* w2,
                   const float* w3, const float* w4, bf16_t* __restrict__ out)
{
    int gid = blockIdx.x * 256 + threadIdx.x;       // < 5*1024*7*256 = 9175040
    int i = gid / 1835008;
    int w = gid - i * 1835008;
    int o = w / 1792;
    int r2 = w - o * 1792;
    int kk = r2 >> 8, c4 = (r2 & 255) * 4;
    const float* ws[5] = {w0, w1, w2, w3, w4};
    const float* src = ws[i] + (size_t)o * 7168 + c4 * 7 + kk;
    bf16x4v v = { (bf16_t)src[0], (bf16_t)src[7], (bf16_t)src[14], (bf16_t)src[21] };
    *(bf16x4v*)&out[((size_t)(i * 7 + kk) << 20) + (o << 10) + c4] = v;
}

// conv biases -> cball[5120]; bq||bk -> qkbias[2048]; zero page init
__global__ __launch_bounds__(256)
void gather_bias(const float* b0, const float* b1, const float* b2,
                 const float* b3, const float* b4,
                 const float* bq, const float* bk,
                 float* __restrict__ out, float* __restrict__ qkbias,
                 bf16_t* __restrict__ zp)
{
    int idx = blockIdx.x * 256 + threadIdx.x;       // grid 28 -> 7168
    if (blockIdx.x == 0 && threadIdx.x < 32) zp[threadIdx.x] = (bf16_t)0.0f;
    if (idx < 5120) {
        const float* bs[5] = {b0, b1, b2, b3, b4};
        out[idx] = bs[idx >> 10][idx & 1023];
    } else {
        int j = idx - 5120;                          // < 2048
        qkbias[j] = (j < 1024) ? bq[j] : bk[j - 1024];
    }
}

// ---------------------------------------------------------------------------
// bf16 MFMA NT GEMM: out[n, m] = sum_k A[n,k]*B[m,k] + bias[...]
// Tile NRx128 (NR in {128,64}), BK=32, 4 waves, 16x16x32 MFMA.
//
// Depth-2 pipelined staging, 3 LDS buffers (48/36 KB -> 3-4 blocks/CU;
// depth-3/4-buffer was measured WORSE: 64 KB halves occupancy, r4).
// Per K-step: wait vmcnt(tile s) -> barrier -> sched_barrier -> ds_read
// frags(s) -> issue stage(s+2) -> MFMA.  Counted vmcnt, never 0 in steady
// state (vmcnt(4) for NR=128, (3) for NR=64).
//
// LDS slot swizzle: 16B slot ^= (row>>1)&3 on the global source column and
// the ds_read slot -> conflict-free ds_read_b128.
//
// Conv A staging has a wave-uniform slab fast path: a 16-row slab can only
// go OOB within |shift| rows of a 256 boundary; test once per slab (scalar
// branch), branchless address otherwise.
//
// BIAS_ROW: bias indexed by n (row) instead of oc0+m (transposed-out GEMM).
// ---------------------------------------------------------------------------
template<bool CONV, bool OUT_BF16, bool BIAS_ROW = false, int NR = 128>
__global__ __launch_bounds__(256)
void mfma_gemm(const bf16_t* __restrict__ A, const bf16_t* __restrict__ Bw,
               const float* __restrict__ bias, void* __restrict__ outv,
               const bf16_t* __restrict__ zp,
               int Kd, int lda, int ldb, int ldo, int out_col0)
{
    constexpr int FN = NR / 32;                  // 4 (NR=128) or 2 (NR=64)
    __shared__ __align__(16) bf16_t As[3][NR * 32];
    __shared__ __align__(16) bf16_t Bs[3][128 * 32];
    const int t = threadIdx.x;
    const int lane = t & 63, wave = t >> 6;
    const int wn = (wave & 1) * (NR / 2), wm = (wave >> 1) * 64;
    const int q = lane >> 4, lr = lane & 15;
    const int mt = CONV ? (blockIdx.x & 7) : blockIdx.x;
    const int conv_i = CONV ? (blockIdx.x >> 3) : 0;
    const int m0 = mt * 128, n0 = blockIdx.y * NR;
    const int srow = lane >> 2, sseg = lane & 3;           // staging row/16B-seg
    const int sw_seg = sseg ^ ((srow >> 1) & 3);           // swizzled source seg
    const int slotq = (q ^ ((lr >> 1) & 3)) * 8;           // swizzled read slot

    f32x4 acc[FN][4];
    #pragma unroll
    for (int a = 0; a < FN; a++)
        #pragma unroll
        for (int b = 0; b < 4; b++) acc[a][b] = (f32x4){0.f, 0.f, 0.f, 0.f};

    const int ksteps = Kd >> 5;
    const int T = CONV ? ksteps * 7 : ksteps;

    // stage cursor (advanced once per stage call, in issue order)
    int s_tap = 0, s_k0 = 0;
    auto do_stage = [&](int bi) {
        const bf16_t* Bp = CONV ? (Bw + ((size_t)(conv_i * 7 + s_tap) << 20)) : Bw;
        const int shift = CONV ? ((s_tap - 3) << conv_i) : 0;
        #pragma unroll
        for (int p = 0; p < NR / 64; p++) {
            const int slab = p * 64 + wave * 16;   // 16-row slab base
            const bf16_t* ga;
            if (CONV) {
                const int slabN = n0 + slab;               // wave-uniform
                const int inSeg = slabN & 255;             // wave-uniform
                if (inSeg + shift >= 0 && inSeg + shift <= 240) {
                    // whole slab in-bounds: branchless address
                    ga = A + (size_t)(slabN + srow + shift) * lda + s_k0 + sw_seg * 8;
                } else {
                    int n = slabN + srow;
                    int tg = (n & 255) + shift;
                    ga = ((unsigned)tg < 256u)
                       ? A + (size_t)((n & ~255) + tg) * lda + s_k0 + sw_seg * 8
                       : zp + sseg * 8;
                }
            } else {
                ga = A + (size_t)(n0 + slab + srow) * lda + s_k0 + sw_seg * 8;
            }
            gll16(ga, &As[bi][slab * 32]);
        }
        #pragma unroll
        for (int p = 0; p < 2; p++) {
            const int slab = p * 64 + wave * 16;
            const int rr = slab + srow;
            gll16(Bp + (size_t)(m0 + rr) * ldb + s_k0 + sw_seg * 8, &Bs[bi][slab * 32]);
        }
        s_k0 += 32;
        if (CONV && s_k0 == Kd) { s_k0 = 0; s_tap++; }
    };

    // prologue: 2 tiles in flight
    do_stage(0);
    do_stage(1);

    int cur = 0;
    for (int s = 0; s < T; s++) {
        if (s + 1 < T) {
            if constexpr (NR == 128) asm volatile("s_waitcnt vmcnt(4)" ::: "memory");
            else                     asm volatile("s_waitcnt vmcnt(3)" ::: "memory");
        } else {
            asm volatile("s_waitcnt vmcnt(0)" ::: "memory");
        }
        __builtin_amdgcn_s_barrier();
        __builtin_amdgcn_sched_barrier(0);

        // fragments first -- lgkm wait overlaps the stage issue below
        bf16x8 af[FN], bfv[4];
        #pragma unroll
        for (int f = 0; f < FN; f++)
            af[f] = *(bf16x8*)&As[cur][(wn + f * 16 + lr) * 32 + slotq];
        #pragma unroll
        for (int f = 0; f < 4; f++)
            bfv[f] = *(bf16x8*)&Bs[cur][(wm + f * 16 + lr) * 32 + slotq];

        int nb = cur + 2; if (nb >= 3) nb -= 3;
        if (s + 2 < T) do_stage(nb);

        __builtin_amdgcn_s_setprio(1);
        #pragma unroll
        for (int fn = 0; fn < FN; fn++)
            #pragma unroll
            for (int fm = 0; fm < 4; fm++)
                acc[fn][fm] = __builtin_amdgcn_mfma_f32_16x16x32_bf16(
                    af[fn], bfv[fm], acc[fn][fm], 0, 0, 0);
        __builtin_amdgcn_s_setprio(0);
        cur++; if (cur == 3) cur = 0;
    }

    const int oc0 = CONV ? (conv_i << 10) : out_col0;
    #pragma unroll
    for (int fn = 0; fn < FN; fn++) {
        #pragma unroll
        for (int r = 0; r < 4; r++) {
            int n = n0 + wn + fn * 16 + q * 4 + r;
            #pragma unroll
            for (int fm = 0; fm < 4; fm++) {
                int m = m0 + wm + fm * 16 + lr;
                float v = acc[fn][fm][r];
                if (bias) v += bias[BIAS_ROW ? n : (oc0 + m)];
                if (OUT_BF16)
                    ((bf16_t*)outv)[(size_t)n * ldo + oc0 + m] = (bf16_t)v;
                else
                    ((float*)outv)[(size_t)n * ldo + oc0 + m] = v;
            }
        }
    }
}

// ---------------------------------------------------------------------------
// LayerNorm (eps 1e-5) + exact GELU, in place on z (fp32) + bf16 copy zb.
// ---------------------------------------------------------------------------
__global__ __launch_bounds__(256)
void ln_gelu(float* __restrict__ z, bf16_t* __restrict__ zb,
             const float* __restrict__ g, const float* __restrict__ b)
{
    __shared__ float r1[256], r2[256];
    const int n = blockIdx.x, t = threadIdx.x;
    float* row = z + (size_t)n * 1024;
    float x[4], s = 0.f, s2 = 0.f;
    #pragma unroll
    for (int u = 0; u < 4; u++) {
        x[u] = row[t + u * 256];
        s += x[u]; s2 += x[u] * x[u];
    }
    r1[t] = s; r2[t] = s2;
    __syncthreads();
    for (int off = 128; off > 0; off >>= 1) {
        if (t < off) { r1[t] += r1[t + off]; r2[t] += r2[t + off]; }
        __syncthreads();
    }
    const float mu  = r1[0] * (1.0f / 1024.0f);
    const float var = r2[0] * (1.0f / 1024.0f) - mu * mu;
    const float rstd = rsqrtf(var + 1e-5f);
    #pragma unroll
    for (int u = 0; u < 4; u++) {
        int c = t + u * 256;
        float y = (x[u] - mu) * rstd * g[c] + b[c];
        float gv = 0.5f * y * (1.0f + erff(y * 0.70710678118654752f));
        row[c] = gv;
        zb[(size_t)n * 1024 + c] = (bf16_t)gv;
    }
}

// ---------------------------------------------------------------------------
// MFMA flash attention.
// Grid (2 i-tiles x 16 heads x 8 batch) = 256 blocks, 4 waves.
// q,k: interleaved QK buffer [2048][2048] bf16 (cols 0-1023 = Q, 1024-2047 = K);
// vt: [1024 dims][2048 tokens] bf16.  ctx: [2048][1024].
// LDS XOR-swizzled (16B slot ^= row&7).
// ---------------------------------------------------------------------------
__global__ __launch_bounds__(256)
void attn_mfma(const bf16_t* __restrict__ qg, const bf16_t* __restrict__ kg,
               const bf16_t* __restrict__ vt, bf16_t* __restrict__ ctx)
{
    const int it = blockIdx.x, h = blockIdx.y, bb = blockIdx.z;
    const int t = threadIdx.x, lane = t & 63, wave = t >> 6;
    const int q4 = lane >> 4, lr = lane & 15;
    const size_t qkbase = (size_t)bb * 256 * 2048 + (size_t)h * 64;

    __shared__ __align__(16) bf16_t Qs[4][32 * 64];   // per-wave Q rows
    __shared__ __align__(16) bf16_t Ks[64 * 64];      // K chunk  [j][d]
    __shared__ __align__(16) bf16_t Vs[64 * 64];      // Vt chunk [d][j]
    __shared__ __align__(16) bf16_t Ps[4][32 * 64];   // per-wave P tile [i][j]

    // ---- stage Q (128 rows x 64, swizzled), cooperative ----
    {
        const int itbase = it * 128;
        #pragma unroll
        for (int rep = 0; rep < 4; rep++) {
            int idx = rep * 256 + t;
            int rl = idx >> 3, seg = idx & 7;
            bf16x8 v = *(const bf16x8*)&qg[qkbase + (size_t)(itbase + rl) * 2048 + seg * 8];
            *(bf16x8*)&Qs[rl >> 5][(rl & 31) * 64 + ((seg ^ (rl & 7)) << 3)] = v;
        }
    }

    f32x4 o[2][4];                 // O accum: [fn rows][fd d-frag]
    float mrow[2][4], lrow[2][4];  // online softmax state per (fn, r)
    #pragma unroll
    for (int fn = 0; fn < 2; fn++)
        #pragma unroll
        for (int x = 0; x < 4; x++) {
            o[fn][x] = (f32x4){0.f, 0.f, 0.f, 0.f};
            mrow[fn][x] = -1e30f; lrow[fn][x] = 0.f;
        }

    for (int j0 = 0; j0 < 256; j0 += 64) {
        __syncthreads();           // prev chunk's K/V reads done (also covers Q stage)
        // ---- stage K chunk [64 j][64 d] and Vt chunk [64 d][64 j], swizzled ----
        #pragma unroll
        for (int rep = 0; rep < 2; rep++) {
            int idx = rep * 256 + t;
            int rl = idx >> 3, seg = idx & 7;
            bf16x8 kv = *(const bf16x8*)&kg[qkbase + (size_t)(j0 + rl) * 2048 + seg * 8];
            *(bf16x8*)&Ks[rl * 64 + ((seg ^ (rl & 7)) << 3)] = kv;
            bf16x8 vv = *(const bf16x8*)&vt[(size_t)(h * 64 + rl) * 2048 + bb * 256 + j0 + seg * 8];
            *(bf16x8*)&Vs[rl * 64 + ((seg ^ (rl & 7)) << 3)] = vv;
        }
        __syncthreads();

        // ---- S = Q K^T  (wave's 32 rows x 64 j) ----
        f32x4 s[2][4];
        #pragma unroll
        for (int fn = 0; fn < 2; fn++)
            #pragma unroll
            for (int fm = 0; fm < 4; fm++) s[fn][fm] = (f32x4){0.f, 0.f, 0.f, 0.f};
        #pragma unroll
        for (int kk = 0; kk < 2; kk++) {
            bf16x8 aq[2], bk[4];
            #pragma unroll
            for (int fn = 0; fn < 2; fn++) {
                int row = fn * 16 + lr;
                aq[fn] = *(bf16x8*)&Qs[wave][row * 64 + (((kk * 4 + q4) ^ (row & 7)) << 3)];
            }
            #pragma unroll
            for (int fm = 0; fm < 4; fm++) {
                int row = fm * 16 + lr;
                bk[fm] = *(bf16x8*)&Ks[row * 64 + (((kk * 4 + q4) ^ (row & 7)) << 3)];
            }
            #pragma unroll
            for (int fn = 0; fn < 2; fn++)
                #pragma unroll
                for (int fm = 0; fm < 4; fm++)
                    s[fn][fm] = __builtin_amdgcn_mfma_f32_16x16x32_bf16(
                        aq[fn], bk[fm], s[fn][fm], 0, 0, 0);
        }

        // ---- online softmax update + P (bf16) into wave-private LDS ----
        #pragma unroll
        for (int fn = 0; fn < 2; fn++) {
            #pragma unroll
            for (int r = 0; r < 4; r++) {
                float sv[4];
                #pragma unroll
                for (int fm = 0; fm < 4; fm++) sv[fm] = s[fn][fm][r] * 0.125f;
                float rm = fmaxf(fmaxf(sv[0], sv[1]), fmaxf(sv[2], sv[3]));
                rm = fmaxf(rm, __shfl_xor(rm, 1));
                rm = fmaxf(rm, __shfl_xor(rm, 2));
                rm = fmaxf(rm, __shfl_xor(rm, 4));
                rm = fmaxf(rm, __shfl_xor(rm, 8));
                float mold = mrow[fn][r];
                float mnew = fmaxf(mold, rm);
                float scl = __expf(mold - mnew);
                mrow[fn][r] = mnew;
                int prow = fn * 16 + q4 * 4 + r;
                float psum = 0.f;
                #pragma unroll
                for (int fm = 0; fm < 4; fm++) {
                    float p = __expf(sv[fm] - mnew);
                    psum += p;
                    int col = fm * 16 + lr;
                    Ps[wave][prow * 64 + (col ^ ((prow & 7) << 3))] = (bf16_t)p;
                }
                psum += __shfl_xor(psum, 1);
                psum += __shfl_xor(psum, 2);
                psum += __shfl_xor(psum, 4);
                psum += __shfl_xor(psum, 8);
                lrow[fn][r] = lrow[fn][r] * scl + psum;
                #pragma unroll
                for (int fd = 0; fd < 4; fd++) o[fn][fd][r] *= scl;
            }
        }

        // ---- O += P V  (wave-private Ps: in-order same-wave DS, no barrier) ----
        #pragma unroll
        for (int kk = 0; kk < 2; kk++) {
            bf16x8 ap[2], bvf[4];
            #pragma unroll
            for (int fn = 0; fn < 2; fn++) {
                int row = fn * 16 + lr;
                ap[fn] = *(bf16x8*)&Ps[wave][row * 64 + (((kk * 4 + q4) ^ (row & 7)) << 3)];
            }
            #pragma unroll
            for (int fd = 0; fd < 4; fd++) {
                int row = fd * 16 + lr;
                bvf[fd] = *(bf16x8*)&Vs[row * 64 + (((kk * 4 + q4) ^ (row & 7)) << 3)];
            }
            #pragma unroll
            for (int fn = 0; fn < 2; fn++)
                #pragma unroll
                for (int fd = 0; fd < 4; fd++)
                    o[fn][fd] = __builtin_amdgcn_mfma_f32_16x16x32_bf16(
                        ap[fn], bvf[fd], o[fn][fd], 0, 0, 0);
        }
    }

    // ---- epilogue: normalize, write ctx ----
    const int i0 = it * 128 + wave * 32;
    #pragma unroll
    for (int fn = 0; fn < 2; fn++) {
        #pragma unroll
        for (int r = 0; r < 4; r++) {
            float inv = 1.0f / lrow[fn][r];
            int row = i0 + fn * 16 + q4 * 4 + r;
            #pragma unroll
            for (int fd = 0; fd < 4; fd++) {
                int col = h * 64 + fd * 16 + lr;
                ctx[(size_t)bb * 262144 + (size_t)row * 1024 + col] =
                    (bf16_t)(o[fn][fd][r] * inv);
            }
        }
    }
}

// ---------------------------------------------------------------------------
// GAT logits, TRANSPOSED out: e1t[h][n] = hg[n,h,:].a1 ; e2t likewise.
// ---------------------------------------------------------------------------
__global__ __launch_bounds__(256)
void gat_e(const float* __restrict__ hg, const float* __restrict__ a1,
           const float* __restrict__ a2, float* __restrict__ e1t,
           float* __restrict__ e2t)
{
    int id = blockIdx.x * 256 + threadIdx.x;  // < 16384
    int h = id >> 11, n = id & 2047;
    const float* hr = hg + (size_t)n * 1024 + h * 128;
    float s1 = 0.f, s2 = 0.f;
    for (int d = 0; d < 128; d += 4) {
        float4 x = *(const float4*)&hr[d];
        float4 u1 = *(const float4*)&a1[d];
        float4 u2 = *(const float4*)&a2[d];
        s1 += x.x * u1.x + x.y * u1.y + x.z * u1.z + x.w * u1.w;
        s2 += x.x * u2.x + x.y * u2.y + x.z * u2.z + x.w * u2.w;
    }
    e1t[id] = s1; e2t[id] = s2;
}

// ---------------------------------------------------------------------------
// Transpose hg (2048 x 1024, fp32) -> hgT (1024 x 2048, bf16), 32x32 tiles.
// ---------------------------------------------------------------------------
__global__ __launch_bounds__(256)
void transpose_hg(const float* __restrict__ in, bf16_t* __restrict__ out)
{
    __shared__ float tile[32][33];
    const int t = threadIdx.x;
    const int j0 = blockIdx.x * 32, c0 = blockIdx.y * 32;
    {
        int jl = t >> 3, cl = (t & 7) * 4;
        float4 v = *(const float4*)(in + (size_t)(j0 + jl) * 1024 + c0 + cl);
        tile[jl][cl] = v.x; tile[jl][cl + 1] = v.y;
        tile[jl][cl + 2] = v.z; tile[jl][cl + 3] = v.w;
    }
    __syncthreads();
    {
        int cl = t >> 3, jl = (t & 7) * 4;
        bf16x4v o = { (bf16_t)tile[jl][cl], (bf16_t)tile[jl + 1][cl],
                      (bf16_t)tile[jl + 2][cl], (bf16_t)tile[jl + 3][cl] };
        *(bf16x4v*)&out[(size_t)(c0 + cl) * 2048 + j0 + jl] = o;
    }
}

// ---------------------------------------------------------------------------
// Fused GAT softmax-aggregate via MFMA.  Grid (32, 8) x 256.
// Exact row max without a scan pass: leaky_relu is monotone, so
// m_i = leaky(e1_i + max_j e2_j); the denominator is accumulated as per-thread
// register partial sums inside the P-build loop (thread->(i,jg) mapping is
// j0-invariant) and reduced with 16-lane shuffles at the end.
// ---------------------------------------------------------------------------
__global__ __launch_bounds__(256)
void gat_agg_mfma(const bf16_t* __restrict__ hgT, const float* __restrict__ e1t,
                  const float* __restrict__ e2t, const float* __restrict__ feat,
                  float* __restrict__ outp)
{
    const int it = blockIdx.x, h = blockIdx.y;
    const int i0 = it * 64;
    __shared__ float e2s[2048];
    __shared__ float e1s[64], mS[64], lSinv[64];
    __shared__ float wmax[4];
    __shared__ __align__(16) bf16_t Ps[64 * 136];
    __shared__ __align__(16) bf16_t Hs[128 * 136];
    const int t = threadIdx.x;
    const int lane = t & 63, wave = t >> 6;
    const int q = lane >> 4, lr = lane & 15;
    const int wm = wave * 32;

    // stage e2 row + block-wide max(e2)
    float lmax = -1e30f;
    for (int idx = t; idx < 2048; idx += 256) {
        float v = e2t[h * 2048 + idx];
        e2s[idx] = v;
        lmax = fmaxf(lmax, v);
    }
    if (t < 64) e1s[t] = e1t[h * 2048 + i0 + t];
    #pragma unroll
    for (int d = 1; d < 64; d <<= 1) lmax = fmaxf(lmax, __shfl_xor(lmax, d));
    if (lane == 0) wmax[wave] = lmax;
    __syncthreads();
    {
        float maxE2 = fmaxf(fmaxf(wmax[0], wmax[1]), fmaxf(wmax[2], wmax[3]));
        if (t < 64) {
            float x = e1s[t] + maxE2;
            mS[t] = (x >= 0.f) ? x : 0.2f * x;     // exact row max of leaky(e1+e2)
        }
    }
    __syncthreads();

    f32x4 acc[4][2];
    #pragma unroll
    for (int a = 0; a < 4; a++)
        #pragma unroll
        for (int b = 0; b < 2; b++) acc[a][b] = (f32x4){0.f, 0.f, 0.f, 0.f};
    float psum[4] = {0.f, 0.f, 0.f, 0.f};          // per-(i,jg) denom partials

    for (int j0 = 0; j0 < 2048; j0 += 128) {
        for (int idx = t; idx < 2048; idx += 256) {
            int d = idx >> 4, seg = idx & 15;
            *(bf16x8*)&Hs[d * 136 + seg * 8] =
                *(const bf16x8*)&hgT[(size_t)(h * 128 + d) * 2048 + j0 + seg * 8];
        }
        #pragma unroll
        for (int rep = 0; rep < 4; rep++) {
            int idx = rep * 256 + t;
            int i = idx >> 4, jg = idx & 15;
            float ei = e1s[i], mi = mS[i];
            bf16x8 pv;
            #pragma unroll
            for (int u = 0; u < 8; u++) {
                float x = ei + e2s[j0 + jg * 8 + u];
                x = (x >= 0.f) ? x : 0.2f * x;
                float p = __expf(x - mi);
                psum[rep] += p;
                pv[u] = (bf16_t)p;
            }
            *(bf16x8*)&Ps[i * 136 + jg * 8] = pv;
        }
        __syncthreads();
        #pragma unroll
        for (int kb = 0; kb < 4; kb++) {
            bf16x8 af[4], bf2[2];
            #pragma unroll
            for (int fn = 0; fn < 4; fn++)
                af[fn] = *(bf16x8*)&Ps[(fn * 16 + lr) * 136 + kb * 32 + q * 8];
            #pragma unroll
            for (int fm = 0; fm < 2; fm++)
                bf2[fm] = *(bf16x8*)&Hs[(wm + fm * 16 + lr) * 136 + kb * 32 + q * 8];
            #pragma unroll
            for (int fn = 0; fn < 4; fn++)
                #pragma unroll
                for (int fm = 0; fm < 2; fm++)
                    acc[fn][fm] = __builtin_amdgcn_mfma_f32_16x16x32_bf16(
                        af[fn], bf2[fm], acc[fn][fm], 0, 0, 0);
        }
        __syncthreads();
    }

    // reduce denom partials: 16 consecutive threads share a row
    #pragma unroll
    for (int rep = 0; rep < 4; rep++) {
        float v = psum[rep];
        v += __shfl_xor(v, 1);
        v += __shfl_xor(v, 2);
        v += __shfl_xor(v, 4);
        v += __shfl_xor(v, 8);
        if ((t & 15) == 0) lSinv[rep * 16 + (t >> 4)] = 1.0f / v;
    }
    __syncthreads();

    #pragma unroll
    for (int fn = 0; fn < 4; fn++) {
        #pragma unroll
        for (int r = 0; r < 4; r++) {
            int il = fn * 16 + q * 4 + r;
            int i = i0 + il;
            float inv = lSinv[il];
            #pragma unroll
            for (int fm = 0; fm < 2; fm++) {
                int col = h * 128 + wm + fm * 16 + lr;
                float v = acc[fn][fm][r] * inv;
                v = (v > 0.f) ? v : (expf(v) - 1.0f);
                size_t off = (size_t)i * 1024 + col;
                outp[off] = v + feat[off];
            }
        }
    }
}

// ---------------------------------------------------------------------------
extern "C" void kernel_launch(void* const* d_in, const int* in_sizes, int n_in,
                              void* d_out, int out_size, void* d_ws, size_t ws_size,
                              hipStream_t stream)
{
    const float* feat = (const float*)d_in[0];
    const float *cw[5], *cb[5];
    if (in_sizes[2] == 1024) {
        for (int i = 0; i < 5; i++) { cw[i] = (const float*)d_in[1 + 2*i]; cb[i] = (const float*)d_in[2 + 2*i]; }
    } else {
        for (int i = 0; i < 5; i++) { cw[i] = (const float*)d_in[1 + i];   cb[i] = (const float*)d_in[6 + i]; }
    }
    const float* fp_w = (const float*)d_in[11];
    const float* fp_b = (const float*)d_in[12];
    const float* ln_g = (const float*)d_in[13];
    const float* ln_b = (const float*)d_in[14];
    const float* wq = (const float*)d_in[15]; const float* bq = (const float*)d_in[16];
    const float* wk = (const float*)d_in[17]; const float* bk = (const float*)d_in[18];
    const float* wv = (const float*)d_in[19]; const float* bv = (const float*)d_in[20];
    const float* wo = (const float*)d_in[21]; const float* bo = (const float*)d_in[22];
    const float* gat_w = (const float*)d_in[23]; const float* gat_b = (const float*)d_in[24];
    const float* ga1 = (const float*)d_in[25]; const float* ga2 = (const float*)d_in[26];
    float* outp = (float*)d_out;

    // ---- workspace layout (~118 MiB) ----
    char* wsb = (char*)d_ws;
    bf16_t* xb    = (bf16_t*)(wsb);                     //  4,194,304
    bf16_t* msb   = (bf16_t*)(wsb + 4194304);           // 20,971,520
    bf16_t* wcb   = (bf16_t*)(wsb + 25165824);          // 73,400,320
    float*  zf    = (float*) (wsb + 98566144);          //  8,388,608
    bf16_t* zb    = (bf16_t*)(wsb + 106954752);         //  4,194,304
    bf16_t* qb    = (bf16_t*)(wsb + 111149056);         //  4,194,304
    bf16_t* kb    = (bf16_t*)(wsb + 115343360);         //  4,194,304
    bf16_t* vb    = (bf16_t*)(wsb + 119537664);         //  4,194,304 (Vt [1024][2048])
    float*  cball = (float*) (wsb + 123731968);         //     20,480
    float*  e1t   = (float*) (wsb + 123752448);         //     65,536
    float*  e2t   = (float*) (wsb + 123817984);         //     65,536
    bf16_t* zpage = (bf16_t*)(wsb + 123883520);         //         64
    // aliases (stream-ordered reuse):
    bf16_t* fpwb = wcb;                 // wcb dead after conv GEMM
    bf16_t* wqb  = wcb + 5242880;       // wq||wk contiguous for merged QK GEMM
    bf16_t* wkb  = wqb + 1048576;
    bf16_t* wvb  = wkb + 1048576;
    bf16_t* wob  = wvb + 1048576;
    bf16_t* gwb  = wob + 1048576;
    bf16_t* qkb  = qb;                  // merged QK output [2048][2048] (qb+kb)
    float*  qkbias = e1t;               // e1t not needed until step 10
    bf16_t* ctxb = zb;                  // zb dead after QK/V projections
    bf16_t* attb = kb;                  // qkb dead after attn
    float*  hgb  = zf;                  // zf dead after ln_gelu
    bf16_t* hgtb = msb;                 // msb dead after fusion GEMM

    const dim3 blk(256);

    // 1) feat conversion + conv weight reorder + bias gathers + zero page
    cvt_f32_bf16<<<dim3(2048), blk, 0, stream>>>(feat, xb, 524288);
    reorder_convw<<<dim3(35840), blk, 0, stream>>>(cw[0], cw[1], cw[2], cw[3], cw[4], wcb);
    gather_bias<<<dim3(28), blk, 0, stream>>>(cb[0], cb[1], cb[2], cb[3], cb[4],
                                              bq, bk, cball, qkbias, zpage);

    // 2) all 5 dilated convs, one MFMA launch -> msb (bf16, ld 5120)
    mfma_gemm<true, true><<<dim3(40, 16), blk, 0, stream>>>(
        xb, wcb, cball, msb, zpage, 1024, 1024, 1024, 5120, 0);

    // 3) remaining weight conversions (single launch; aliases wcb, so after conv)
    cvt_multi<<<dim3(10240), blk, 0, stream>>>(fp_w, wq, wk, wv, wo, gat_w,
                                               fpwb, wqb, wkb, wvb, wob, gwb);

    // 4) fusion projection -> zf (fp32); 64-row tiles -> 256 blocks
    mfma_gemm<false, false, false, 64><<<dim3(8, 32), blk, 0, stream>>>(
        msb, fpwb, fp_b, zf, zpage, 5120, 5120, 5120, 1024, 0);

    // 5) LN + GELU -> zf (fp32) and zb (bf16)
    ln_gelu<<<dim3(2048), blk, 0, stream>>>(zf, zb, ln_g, ln_b);

    // 6) merged Q+K projection -> qkb [2048][2048]; V operand-swapped -> Vt
    mfma_gemm<false, true><<<dim3(16, 16), blk, 0, stream>>>(
        zb, wqb, qkbias, qkb, zpage, 1024, 1024, 1024, 2048, 0);
    mfma_gemm<false, true, true, 64><<<dim3(16, 16), blk, 0, stream>>>(
        wvb, zb, bv, vb, zpage, 1024, 1024, 1024, 2048, 0);

    // 7) MFMA flash attention -> ctxb (bf16)
    attn_mfma<<<dim3(2, 16, 8), blk, 0, stream>>>(qkb, qkb + 1024, vb, ctxb);

    // 8) output projection -> attb (bf16); 64-row tiles
    mfma_gemm<false, true, false, 64><<<dim3(8, 32), blk, 0, stream>>>(
        ctxb, wob, bo, attb, zpage, 1024, 1024, 1024, 1024, 0);

    // 9) GAT projection -> hgb (fp32); 64-row tiles
    mfma_gemm<false, false, false, 64><<<dim3(8, 32), blk, 0, stream>>>(
        attb, gwb, gat_b, hgb, zpage, 1024, 1024, 1024, 1024, 0);

    // 10) GAT: transpose hg, logits, fused softmax-aggregate (MFMA)
    transpose_hg<<<dim3(64, 32), blk, 0, stream>>>(hgb, hgtb);
    gat_e<<<dim3(64), blk, 0, stream>>>(hgb, ga1, ga2, e1t, e2t);
    gat_agg_mfma<<<dim3(32, 8), blk, 0, stream>>>(hgtb, e1t, e2t, feat, outp);
}

// Round 6
// 658.608 us; speedup vs baseline: 1.2633x; 1.1419x over previous
//
#include <hip/hip_runtime.h>
#include <hip/hip_bf16.h>

typedef __bf16 bf16_t;
typedef bf16_t bf16x8 __attribute__((ext_vector_type(8)));
typedef bf16_t bf16x4v __attribute__((ext_vector_type(4)));
typedef float f32x4 __attribute__((ext_vector_type(4)));

// async 16B global->LDS (direct, no VGPR round trip)
__device__ __forceinline__ void gll16(const bf16_t* g, bf16_t* l) {
    __builtin_amdgcn_global_load_lds(
        (const __attribute__((address_space(1))) unsigned int*)g,
        (__attribute__((address_space(3))) unsigned int*)l, 16, 0, 0);
}

// ---------------------------------------------------------------------------
// fp32 -> bf16 elementwise (n multiple of 4)
// ---------------------------------------------------------------------------
__global__ __launch_bounds__(256)
void cvt_f32_bf16(const float* __restrict__ in, bf16_t* __restrict__ out, int n4)
{
    int i = blockIdx.x * 256 + threadIdx.x;
    if (i < n4) {
        float4 v = ((const float4*)in)[i];
        bf16x4v o = { (bf16_t)v.x, (bf16_t)v.y, (bf16_t)v.z, (bf16_t)v.w };
        *(bf16x4v*)&out[i * 4] = o;
    }
}

// ---------------------------------------------------------------------------
// Merged fp32->bf16 for 5 weight tensors (fp_w + wq/wk/wv/gat_w), 1 launch.
// (wo is handled by transpose_w instead.)
// ---------------------------------------------------------------------------
__global__ __launch_bounds__(256)
void cvt_multi(const float* __restrict__ fpw, const float* __restrict__ wq,
               const float* __restrict__ wk, const float* __restrict__ wv,
               const float* __restrict__ gw,
               bf16_t* __restrict__ fpwb, bf16_t* __restrict__ wqb,
               bf16_t* __restrict__ wkb, bf16_t* __restrict__ wvb,
               bf16_t* __restrict__ gwb)
{
    int id = blockIdx.x * 256 + threadIdx.x;    // < 2359296
    const float* src; bf16_t* dst; int off;
    if (id < 1310720) { src = fpw; dst = fpwb; off = id; }
    else {
        int id3 = id - 1310720;
        int w = id3 >> 18; off = id3 & 262143;
        const float* ss[4] = {wq, wk, wv, gw};
        bf16_t* dd[4] = {wqb, wkb, wvb, gwb};
        src = ss[w]; dst = dd[w];
    }
    float4 v = ((const float4*)src)[off];
    bf16x4v o = { (bf16_t)v.x, (bf16_t)v.y, (bf16_t)v.z, (bf16_t)v.w };
    *(bf16x4v*)&dst[off * 4] = o;
}

// ---------------------------------------------------------------------------
// Reorder conv weights (O,C,7) fp32 -> bf16 planes [(i*7+kk)][o][c].
// (r3 version: contiguous 28B read per thread; 7 coalesced 2B store planes.
//  The stride-112B 4-load variant measured ~slower -- reverted.)
// ---------------------------------------------------------------------------
__global__ __launch_bounds__(256)
void reorder_convw(const float* w0, const float* w1, const float* w2,
                   const float* w3, const float* w4, bf16_t* __restrict__ out)
{
    int gid = blockIdx.x * 256 + threadIdx.x;       // < 5*1024*1024
    int i = gid >> 20, rem = gid & 1048575;
    int o = rem >> 10, c = rem & 1023;
    const float* ws[5] = {w0, w1, w2, w3, w4};
    const float* src = ws[i] + (size_t)o * 7168 + c * 7;
    #pragma unroll
    for (int kk = 0; kk < 7; kk++)
        out[((size_t)(i * 7 + kk) << 20) + (o << 10) + c] = (bf16_t)src[kk];
}

// conv biases -> cball[5120]; bq||bk -> qkbias[2048]; zero page init
__global__ __launch_bounds__(256)
void gather_bias(const float* b0, const float* b1, const float* b2,
                 const float* b3, const float* b4,
                 const float* bq, const float* bk,
                 float* __restrict__ out, float* __restrict__ qkbias,
                 bf16_t* __restrict__ zp)
{
    int idx = blockIdx.x * 256 + threadIdx.x;       // grid 28 -> 7168
    if (blockIdx.x == 0 && threadIdx.x < 32) zp[threadIdx.x] = (bf16_t)0.0f;
    if (idx < 5120) {
        const float* bs[5] = {b0, b1, b2, b3, b4};
        out[idx] = bs[idx >> 10][idx & 1023];
    } else {
        int j = idx - 5120;                          // < 2048
        qkbias[j] = (j < 1024) ? bq[j] : bk[j - 1024];
    }
}

// ---------------------------------------------------------------------------
// Transpose wo (1024 x 1024 fp32) -> woT (1024 x 1024 bf16): woT[i][k]=wo[k][i].
// ---------------------------------------------------------------------------
__global__ __launch_bounds__(256)
void transpose_w(const float* __restrict__ in, bf16_t* __restrict__ out)
{
    __shared__ float tile[32][33];
    const int t = threadIdx.x;
    const int j0 = blockIdx.x * 32, c0 = blockIdx.y * 32;
    {
        int jl = t >> 3, cl = (t & 7) * 4;
        float4 v = *(const float4*)(in + (size_t)(j0 + jl) * 1024 + c0 + cl);
        tile[jl][cl] = v.x; tile[jl][cl + 1] = v.y;
        tile[jl][cl + 2] = v.z; tile[jl][cl + 3] = v.w;
    }
    __syncthreads();
    {
        int cl = t >> 3, jl = (t & 7) * 4;
        bf16x4v o = { (bf16_t)tile[jl][cl], (bf16_t)tile[jl + 1][cl],
                      (bf16_t)tile[jl + 2][cl], (bf16_t)tile[jl + 3][cl] };
        *(bf16x4v*)&out[(size_t)(c0 + cl) * 1024 + j0 + jl] = o;
    }
}

// ---------------------------------------------------------------------------
// bc[d] = gat_b[d] + dot(gat_w[d,:], bo)   (folded bias of merged projection)
// One wave per row d; grid 256 x 256thr.
// ---------------------------------------------------------------------------
__global__ __launch_bounds__(256)
void fold_bias(const float* __restrict__ gw, const float* __restrict__ bo,
               const float* __restrict__ gb, float* __restrict__ bc)
{
    const int wave = threadIdx.x >> 6, lane = threadIdx.x & 63;
    const int d = blockIdx.x * 4 + wave;
    const float* row = gw + (size_t)d * 1024;
    float s = 0.f;
    #pragma unroll
    for (int k = lane * 4; k < 1024; k += 256) {
        float4 x = *(const float4*)&row[k];
        float4 a = *(const float4*)&bo[k];
        s += x.x * a.x + x.y * a.y + x.z * a.z + x.w * a.w;
    }
    s += __shfl_xor(s, 1);  s += __shfl_xor(s, 2);  s += __shfl_xor(s, 4);
    s += __shfl_xor(s, 8);  s += __shfl_xor(s, 16); s += __shfl_xor(s, 32);
    if (lane == 0) bc[d] = gb[d] + s;
}

// ---------------------------------------------------------------------------
// bf16 MFMA NT GEMM: out[n, m] = sum_k A[n,k]*B[m,k] + bias[...]
// Tile NRx128 (NR in {128,64}), BK=32, 4 waves, 16x16x32 MFMA.
//
// Depth-2 pipelined staging, 3 LDS buffers (48/36 KB -> 3-4 blocks/CU;
// depth-3/4-buffer was measured WORSE: 64 KB halves occupancy, r4).
// Per K-step: wait vmcnt(tile s) -> barrier -> sched_barrier -> ds_read
// frags(s) -> issue stage(s+2) -> MFMA.  Counted vmcnt, never 0 in steady
// state (vmcnt(4) for NR=128, (3) for NR=64).
//
// LDS slot swizzle: 16B slot ^= (row>>1)&3 on the global source column and
// the ds_read slot -> conflict-free ds_read_b128.
//
// Conv A staging has a wave-uniform slab fast path: a 16-row slab can only
// go OOB within |shift| rows of a 256 boundary; test once per slab (scalar
// branch), branchless address otherwise.
//
// BIAS_ROW: bias indexed by n (row) instead of oc0+m (transposed-out GEMM).
// ---------------------------------------------------------------------------
template<bool CONV, bool OUT_BF16, bool BIAS_ROW = false, int NR = 128>
__global__ __launch_bounds__(256)
void mfma_gemm(const bf16_t* __restrict__ A, const bf16_t* __restrict__ Bw,
               const float* __restrict__ bias, void* __restrict__ outv,
               const bf16_t* __restrict__ zp,
               int Kd, int lda, int ldb, int ldo, int out_col0)
{
    constexpr int FN = NR / 32;                  // 4 (NR=128) or 2 (NR=64)
    __shared__ __align__(16) bf16_t As[3][NR * 32];
    __shared__ __align__(16) bf16_t Bs[3][128 * 32];
    const int t = threadIdx.x;
    const int lane = t & 63, wave = t >> 6;
    const int wn = (wave & 1) * (NR / 2), wm = (wave >> 1) * 64;
    const int q = lane >> 4, lr = lane & 15;
    const int mt = CONV ? (blockIdx.x & 7) : blockIdx.x;
    const int conv_i = CONV ? (blockIdx.x >> 3) : 0;
    const int m0 = mt * 128, n0 = blockIdx.y * NR;
    const int srow = lane >> 2, sseg = lane & 3;           // staging row/16B-seg
    const int sw_seg = sseg ^ ((srow >> 1) & 3);           // swizzled source seg
    const int slotq = (q ^ ((lr >> 1) & 3)) * 8;           // swizzled read slot

    f32x4 acc[FN][4];
    #pragma unroll
    for (int a = 0; a < FN; a++)
        #pragma unroll
        for (int b = 0; b < 4; b++) acc[a][b] = (f32x4){0.f, 0.f, 0.f, 0.f};

    const int ksteps = Kd >> 5;
    const int T = CONV ? ksteps * 7 : ksteps;

    // stage cursor (advanced once per stage call, in issue order)
    int s_tap = 0, s_k0 = 0;
    auto do_stage = [&](int bi) {
        const bf16_t* Bp = CONV ? (Bw + ((size_t)(conv_i * 7 + s_tap) << 20)) : Bw;
        const int shift = CONV ? ((s_tap - 3) << conv_i) : 0;
        #pragma unroll
        for (int p = 0; p < NR / 64; p++) {
            const int slab = p * 64 + wave * 16;   // 16-row slab base
            const bf16_t* ga;
            if (CONV) {
                const int slabN = n0 + slab;               // wave-uniform
                const int inSeg = slabN & 255;             // wave-uniform
                if (inSeg + shift >= 0 && inSeg + shift <= 240) {
                    // whole slab in-bounds: branchless address
                    ga = A + (size_t)(slabN + srow + shift) * lda + s_k0 + sw_seg * 8;
                } else {
                    int n = slabN + srow;
                    int tg = (n & 255) + shift;
                    ga = ((unsigned)tg < 256u)
                       ? A + (size_t)((n & ~255) + tg) * lda + s_k0 + sw_seg * 8
                       : zp + sseg * 8;
                }
            } else {
                ga = A + (size_t)(n0 + slab + srow) * lda + s_k0 + sw_seg * 8;
            }
            gll16(ga, &As[bi][slab * 32]);
        }
        #pragma unroll
        for (int p = 0; p < 2; p++) {
            const int slab = p * 64 + wave * 16;
            const int rr = slab + srow;
            gll16(Bp + (size_t)(m0 + rr) * ldb + s_k0 + sw_seg * 8, &Bs[bi][slab * 32]);
        }
        s_k0 += 32;
        if (CONV && s_k0 == Kd) { s_k0 = 0; s_tap++; }
    };

    // prologue: 2 tiles in flight
    do_stage(0);
    do_stage(1);

    int cur = 0;
    for (int s = 0; s < T; s++) {
        if (s + 1 < T) {
            if constexpr (NR == 128) asm volatile("s_waitcnt vmcnt(4)" ::: "memory");
            else                     asm volatile("s_waitcnt vmcnt(3)" ::: "memory");
        } else {
            asm volatile("s_waitcnt vmcnt(0)" ::: "memory");
        }
        __builtin_amdgcn_s_barrier();
        __builtin_amdgcn_sched_barrier(0);

        // fragments first -- lgkm wait overlaps the stage issue below
        bf16x8 af[FN], bfv[4];
        #pragma unroll
        for (int f = 0; f < FN; f++)
            af[f] = *(bf16x8*)&As[cur][(wn + f * 16 + lr) * 32 + slotq];
        #pragma unroll
        for (int f = 0; f < 4; f++)
            bfv[f] = *(bf16x8*)&Bs[cur][(wm + f * 16 + lr) * 32 + slotq];

        int nb = cur + 2; if (nb >= 3) nb -= 3;
        if (s + 2 < T) do_stage(nb);

        __builtin_amdgcn_s_setprio(1);
        #pragma unroll
        for (int fn = 0; fn < FN; fn++)
            #pragma unroll
            for (int fm = 0; fm < 4; fm++)
                acc[fn][fm] = __builtin_amdgcn_mfma_f32_16x16x32_bf16(
                    af[fn], bfv[fm], acc[fn][fm], 0, 0, 0);
        __builtin_amdgcn_s_setprio(0);
        cur++; if (cur == 3) cur = 0;
    }

    const int oc0 = CONV ? (conv_i << 10) : out_col0;
    #pragma unroll
    for (int fn = 0; fn < FN; fn++) {
        #pragma unroll
        for (int r = 0; r < 4; r++) {
            int n = n0 + wn + fn * 16 + q * 4 + r;
            #pragma unroll
            for (int fm = 0; fm < 4; fm++) {
                int m = m0 + wm + fm * 16 + lr;
                float v = acc[fn][fm][r];
                if (bias) v += bias[BIAS_ROW ? n : (oc0 + m)];
                if (OUT_BF16)
                    ((bf16_t*)outv)[(size_t)n * ldo + oc0 + m] = (bf16_t)v;
                else
                    ((float*)outv)[(size_t)n * ldo + oc0 + m] = v;
            }
        }
    }
}

// ---------------------------------------------------------------------------
// LayerNorm (eps 1e-5) + exact GELU, in place on z (fp32) + bf16 copy zb.
// ---------------------------------------------------------------------------
__global__ __launch_bounds__(256)
void ln_gelu(float* __restrict__ z, bf16_t* __restrict__ zb,
             const float* __restrict__ g, const float* __restrict__ b)
{
    __shared__ float r1[256], r2[256];
    const int n = blockIdx.x, t = threadIdx.x;
    float* row = z + (size_t)n * 1024;
    float x[4], s = 0.f, s2 = 0.f;
    #pragma unroll
    for (int u = 0; u < 4; u++) {
        x[u] = row[t + u * 256];
        s += x[u]; s2 += x[u] * x[u];
    }
    r1[t] = s; r2[t] = s2;
    __syncthreads();
    for (int off = 128; off > 0; off >>= 1) {
        if (t < off) { r1[t] += r1[t + off]; r2[t] += r2[t + off]; }
        __syncthreads();
    }
    const float mu  = r1[0] * (1.0f / 1024.0f);
    const float var = r2[0] * (1.0f / 1024.0f) - mu * mu;
    const float rstd = rsqrtf(var + 1e-5f);
    #pragma unroll
    for (int u = 0; u < 4; u++) {
        int c = t + u * 256;
        float y = (x[u] - mu) * rstd * g[c] + b[c];
        float gv = 0.5f * y * (1.0f + erff(y * 0.70710678118654752f));
        row[c] = gv;
        zb[(size_t)n * 1024 + c] = (bf16_t)gv;
    }
}

// ---------------------------------------------------------------------------
// MFMA flash attention.
// Grid (2 i-tiles x 16 heads x 8 batch) = 256 blocks, 4 waves.
// q,k: interleaved QK buffer [2048][2048] bf16 (cols 0-1023 = Q, 1024-2047 = K);
// vt: [1024 dims][2048 tokens] bf16.  ctx: [2048][1024].
// LDS XOR-swizzled (16B slot ^= row&7).
// ---------------------------------------------------------------------------
__global__ __launch_bounds__(256)
void attn_mfma(const bf16_t* __restrict__ qg, const bf16_t* __restrict__ kg,
               const bf16_t* __restrict__ vt, bf16_t* __restrict__ ctx)
{
    const int it = blockIdx.x, h = blockIdx.y, bb = blockIdx.z;
    const int t = threadIdx.x, lane = t & 63, wave = t >> 6;
    const int q4 = lane >> 4, lr = lane & 15;
    const size_t qkbase = (size_t)bb * 256 * 2048 + (size_t)h * 64;

    __shared__ __align__(16) bf16_t Qs[4][32 * 64];   // per-wave Q rows
    __shared__ __align__(16) bf16_t Ks[64 * 64];      // K chunk  [j][d]
    __shared__ __align__(16) bf16_t Vs[64 * 64];      // Vt chunk [d][j]
    __shared__ __align__(16) bf16_t Ps[4][32 * 64];   // per-wave P tile [i][j]

    // ---- stage Q (128 rows x 64, swizzled), cooperative ----
    {
        const int itbase = it * 128;
        #pragma unroll
        for (int rep = 0; rep < 4; rep++) {
            int idx = rep * 256 + t;
            int rl = idx >> 3, seg = idx & 7;
            bf16x8 v = *(const bf16x8*)&qg[qkbase + (size_t)(itbase + rl) * 2048 + seg * 8];
            *(bf16x8*)&Qs[rl >> 5][(rl & 31) * 64 + ((seg ^ (rl & 7)) << 3)] = v;
        }
    }

    f32x4 o[2][4];                 // O accum: [fn rows][fd d-frag]
    float mrow[2][4], lrow[2][4];  // online softmax state per (fn, r)
    #pragma unroll
    for (int fn = 0; fn < 2; fn++)
        #pragma unroll
        for (int x = 0; x < 4; x++) {
            o[fn][x] = (f32x4){0.f, 0.f, 0.f, 0.f};
            mrow[fn][x] = -1e30f; lrow[fn][x] = 0.f;
        }

    for (int j0 = 0; j0 < 256; j0 += 64) {
        __syncthreads();           // prev chunk's K/V reads done (also covers Q stage)
        // ---- stage K chunk [64 j][64 d] and Vt chunk [64 d][64 j], swizzled ----
        #pragma unroll
        for (int rep = 0; rep < 2; rep++) {
            int idx = rep * 256 + t;
            int rl = idx >> 3, seg = idx & 7;
            bf16x8 kv = *(const bf16x8*)&kg[qkbase + (size_t)(j0 + rl) * 2048 + seg * 8];
            *(bf16x8*)&Ks[rl * 64 + ((seg ^ (rl & 7)) << 3)] = kv;
            bf16x8 vv = *(const bf16x8*)&vt[(size_t)(h * 64 + rl) * 2048 + bb * 256 + j0 + seg * 8];
            *(bf16x8*)&Vs[rl * 64 + ((seg ^ (rl & 7)) << 3)] = vv;
        }
        __syncthreads();

        // ---- S = Q K^T  (wave's 32 rows x 64 j) ----
        f32x4 s[2][4];
        #pragma unroll
        for (int fn = 0; fn < 2; fn++)
            #pragma unroll
            for (int fm = 0; fm < 4; fm++) s[fn][fm] = (f32x4){0.f, 0.f, 0.f, 0.f};
        #pragma unroll
        for (int kk = 0; kk < 2; kk++) {
            bf16x8 aq[2], bk[4];
            #pragma unroll
            for (int fn = 0; fn < 2; fn++) {
                int row = fn * 16 + lr;
                aq[fn] = *(bf16x8*)&Qs[wave][row * 64 + (((kk * 4 + q4) ^ (row & 7)) << 3)];
            }
            #pragma unroll
            for (int fm = 0; fm < 4; fm++) {
                int row = fm * 16 + lr;
                bk[fm] = *(bf16x8*)&Ks[row * 64 + (((kk * 4 + q4) ^ (row & 7)) << 3)];
            }
            #pragma unroll
            for (int fn = 0; fn < 2; fn++)
                #pragma unroll
                for (int fm = 0; fm < 4; fm++)
                    s[fn][fm] = __builtin_amdgcn_mfma_f32_16x16x32_bf16(
                        aq[fn], bk[fm], s[fn][fm], 0, 0, 0);
        }

        // ---- online softmax update + P (bf16) into wave-private LDS ----
        #pragma unroll
        for (int fn = 0; fn < 2; fn++) {
            #pragma unroll
            for (int r = 0; r < 4; r++) {
                float sv[4];
                #pragma unroll
                for (int fm = 0; fm < 4; fm++) sv[fm] = s[fn][fm][r] * 0.125f;
                float rm = fmaxf(fmaxf(sv[0], sv[1]), fmaxf(sv[2], sv[3]));
                rm = fmaxf(rm, __shfl_xor(rm, 1));
                rm = fmaxf(rm, __shfl_xor(rm, 2));
                rm = fmaxf(rm, __shfl_xor(rm, 4));
                rm = fmaxf(rm, __shfl_xor(rm, 8));
                float mold = mrow[fn][r];
                float mnew = fmaxf(mold, rm);
                float scl = __expf(mold - mnew);
                mrow[fn][r] = mnew;
                int prow = fn * 16 + q4 * 4 + r;
                float psum = 0.f;
                #pragma unroll
                for (int fm = 0; fm < 4; fm++) {
                    float p = __expf(sv[fm] - mnew);
                    psum += p;
                    int col = fm * 16 + lr;
                    Ps[wave][prow * 64 + (col ^ ((prow & 7) << 3))] = (bf16_t)p;
                }
                psum += __shfl_xor(psum, 1);
                psum += __shfl_xor(psum, 2);
                psum += __shfl_xor(psum, 4);
                psum += __shfl_xor(psum, 8);
                lrow[fn][r] = lrow[fn][r] * scl + psum;
                #pragma unroll
                for (int fd = 0; fd < 4; fd++) o[fn][fd][r] *= scl;
            }
        }

        // ---- O += P V  (wave-private Ps: in-order same-wave DS, no barrier) ----
        #pragma unroll
        for (int kk = 0; kk < 2; kk++) {
            bf16x8 ap[2], bvf[4];
            #pragma unroll
            for (int fn = 0; fn < 2; fn++) {
                int row = fn * 16 + lr;
                ap[fn] = *(bf16x8*)&Ps[wave][row * 64 + (((kk * 4 + q4) ^ (row & 7)) << 3)];
            }
            #pragma unroll
            for (int fd = 0; fd < 4; fd++) {
                int row = fd * 16 + lr;
                bvf[fd] = *(bf16x8*)&Vs[row * 64 + (((kk * 4 + q4) ^ (row & 7)) << 3)];
            }
            #pragma unroll
            for (int fn = 0; fn < 2; fn++)
                #pragma unroll
                for (int fd = 0; fd < 4; fd++)
                    o[fn][fd] = __builtin_amdgcn_mfma_f32_16x16x32_bf16(
                        ap[fn], bvf[fd], o[fn][fd], 0, 0, 0);
        }
    }

    // ---- epilogue: normalize, write ctx ----
    const int i0 = it * 128 + wave * 32;
    #pragma unroll
    for (int fn = 0; fn < 2; fn++) {
        #pragma unroll
        for (int r = 0; r < 4; r++) {
            float inv = 1.0f / lrow[fn][r];
            int row = i0 + fn * 16 + q4 * 4 + r;
            #pragma unroll
            for (int fd = 0; fd < 4; fd++) {
                int col = h * 64 + fd * 16 + lr;
                ctx[(size_t)bb * 262144 + (size_t)row * 1024 + col] =
                    (bf16_t)(o[fn][fd][r] * inv);
            }
        }
    }
}

// ---------------------------------------------------------------------------
// GAT logits from hgT (bf16, [1024][2048]): e1t[h][n] = sum_d hgT[h*128+d][n]*a1[d].
// Lane-consecutive n -> fully coalesced 128B/wave per d step.
// ---------------------------------------------------------------------------
__global__ __launch_bounds__(256)
void gat_e(const bf16_t* __restrict__ hgT, const float* __restrict__ a1,
           const float* __restrict__ a2, float* __restrict__ e1t,
           float* __restrict__ e2t)
{
    int id = blockIdx.x * 256 + threadIdx.x;  // < 16384
    int h = id >> 11, n = id & 2047;
    const bf16_t* base = hgT + (size_t)(h * 128) * 2048 + n;
    float s1 = 0.f, s2 = 0.f;
    #pragma unroll 4
    for (int d = 0; d < 128; d++) {
        float x = (float)base[(size_t)d * 2048];
        s1 += x * a1[d];
        s2 += x * a2[d];
    }
    e1t[id] = s1; e2t[id] = s2;
}

// ---------------------------------------------------------------------------
// Fused GAT softmax-aggregate via MFMA.  Grid (32, 8) x 256.
// Exact row max without a scan pass: leaky_relu is monotone, so
// m_i = leaky(e1_i + max_j e2_j); the denominator is accumulated as per-thread
// register partial sums inside the P-build loop (thread->(i,jg) mapping is
// j0-invariant) and reduced with 16-lane shuffles at the end.
// ---------------------------------------------------------------------------
__global__ __launch_bounds__(256)
void gat_agg_mfma(const bf16_t* __restrict__ hgT, const float* __restrict__ e1t,
                  const float* __restrict__ e2t, const float* __restrict__ feat,
                  float* __restrict__ outp)
{
    const int it = blockIdx.x, h = blockIdx.y;
    const int i0 = it * 64;
    __shared__ float e2s[2048];
    __shared__ float e1s[64], mS[64], lSinv[64];
    __shared__ float wmax[4];
    __shared__ __align__(16) bf16_t Ps[64 * 136];
    __shared__ __align__(16) bf16_t Hs[128 * 136];
    const int t = threadIdx.x;
    const int lane = t & 63, wave = t >> 6;
    const int q = lane >> 4, lr = lane & 15;
    const int wm = wave * 32;

    // stage e2 row + block-wide max(e2)
    float lmax = -1e30f;
    for (int idx = t; idx < 2048; idx += 256) {
        float v = e2t[h * 2048 + idx];
        e2s[idx] = v;
        lmax = fmaxf(lmax, v);
    }
    if (t < 64) e1s[t] = e1t[h * 2048 + i0 + t];
    #pragma unroll
    for (int d = 1; d < 64; d <<= 1) lmax = fmaxf(lmax, __shfl_xor(lmax, d));
    if (lane == 0) wmax[wave] = lmax;
    __syncthreads();
    {
        float maxE2 = fmaxf(fmaxf(wmax[0], wmax[1]), fmaxf(wmax[2], wmax[3]));
        if (t < 64) {
            float x = e1s[t] + maxE2;
            mS[t] = (x >= 0.f) ? x : 0.2f * x;     // exact row max of leaky(e1+e2)
        }
    }
    __syncthreads();

    f32x4 acc[4][2];
    #pragma unroll
    for (int a = 0; a < 4; a++)
        #pragma unroll
        for (int b = 0; b < 2; b++) acc[a][b] = (f32x4){0.f, 0.f, 0.f, 0.f};
    float psum[4] = {0.f, 0.f, 0.f, 0.f};          // per-(i,jg) denom partials

    for (int j0 = 0; j0 < 2048; j0 += 128) {
        for (int idx = t; idx < 2048; idx += 256) {
            int d = idx >> 4, seg = idx & 15;
            *(bf16x8*)&Hs[d * 136 + seg * 8] =
                *(const bf16x8*)&hgT[(size_t)(h * 128 + d) * 2048 + j0 + seg * 8];
        }
        #pragma unroll
        for (int rep = 0; rep < 4; rep++) {
            int idx = rep * 256 + t;
            int i = idx >> 4, jg = idx & 15;
            float ei = e1s[i], mi = mS[i];
            bf16x8 pv;
            #pragma unroll
            for (int u = 0; u < 8; u++) {
                float x = ei + e2s[j0 + jg * 8 + u];
                x = (x >= 0.f) ? x : 0.2f * x;
                float p = __expf(x - mi);
                psum[rep] += p;
                pv[u] = (bf16_t)p;
            }
            *(bf16x8*)&Ps[i * 136 + jg * 8] = pv;
        }
        __syncthreads();
        #pragma unroll
        for (int kb = 0; kb < 4; kb++) {
            bf16x8 af[4], bf2[2];
            #pragma unroll
            for (int fn = 0; fn < 4; fn++)
                af[fn] = *(bf16x8*)&Ps[(fn * 16 + lr) * 136 + kb * 32 + q * 8];
            #pragma unroll
            for (int fm = 0; fm < 2; fm++)
                bf2[fm] = *(bf16x8*)&Hs[(wm + fm * 16 + lr) * 136 + kb * 32 + q * 8];
            #pragma unroll
            for (int fn = 0; fn < 4; fn++)
                #pragma unroll
                for (int fm = 0; fm < 2; fm++)
                    acc[fn][fm] = __builtin_amdgcn_mfma_f32_16x16x32_bf16(
                        af[fn], bf2[fm], acc[fn][fm], 0, 0, 0);
        }
        __syncthreads();
    }

    // reduce denom partials: 16 consecutive threads share a row
    #pragma unroll
    for (int rep = 0; rep < 4; rep++) {
        float v = psum[rep];
        v += __shfl_xor(v, 1);
        v += __shfl_xor(v, 2);
        v += __shfl_xor(v, 4);
        v += __shfl_xor(v, 8);
        if ((t & 15) == 0) lSinv[rep * 16 + (t >> 4)] = 1.0f / v;
    }
    __syncthreads();

    #pragma unroll
    for (int fn = 0; fn < 4; fn++) {
        #pragma unroll
        for (int r = 0; r < 4; r++) {
            int il = fn * 16 + q * 4 + r;
            int i = i0 + il;
            float inv = lSinv[il];
            #pragma unroll
            for (int fm = 0; fm < 2; fm++) {
                int col = h * 128 + wm + fm * 16 + lr;
                float v = acc[fn][fm][r] * inv;
                v = (v > 0.f) ? v : (expf(v) - 1.0f);
                size_t off = (size_t)i * 1024 + col;
                outp[off] = v + feat[off];
            }
        }
    }
}

// ---------------------------------------------------------------------------
extern "C" void kernel_launch(void* const* d_in, const int* in_sizes, int n_in,
                              void* d_out, int out_size, void* d_ws, size_t ws_size,
                              hipStream_t stream)
{
    const float* feat = (const float*)d_in[0];
    const float *cw[5], *cb[5];
    if (in_sizes[2] == 1024) {
        for (int i = 0; i < 5; i++) { cw[i] = (const float*)d_in[1 + 2*i]; cb[i] = (const float*)d_in[2 + 2*i]; }
    } else {
        for (int i = 0; i < 5; i++) { cw[i] = (const float*)d_in[1 + i];   cb[i] = (const float*)d_in[6 + i]; }
    }
    const float* fp_w = (const float*)d_in[11];
    const float* fp_b = (const float*)d_in[12];
    const float* ln_g = (const float*)d_in[13];
    const float* ln_b = (const float*)d_in[14];
    const float* wq = (const float*)d_in[15]; const float* bq = (const float*)d_in[16];
    const float* wk = (const float*)d_in[17]; const float* bk = (const float*)d_in[18];
    const float* wv = (const float*)d_in[19]; const float* bv = (const float*)d_in[20];
    const float* wo = (const float*)d_in[21]; const float* bo = (const float*)d_in[22];
    const float* gat_w = (const float*)d_in[23]; const float* gat_b = (const float*)d_in[24];
    const float* ga1 = (const float*)d_in[25]; const float* ga2 = (const float*)d_in[26];
    float* outp = (float*)d_out;

    // ---- workspace layout (~118 MiB) ----
    char* wsb = (char*)d_ws;
    bf16_t* xb    = (bf16_t*)(wsb);                     //  4,194,304
    bf16_t* msb   = (bf16_t*)(wsb + 4194304);           // 20,971,520
    bf16_t* wcb   = (bf16_t*)(wsb + 25165824);          // 73,400,320
    float*  zf    = (float*) (wsb + 98566144);          //  8,388,608
    bf16_t* zb    = (bf16_t*)(wsb + 106954752);         //  4,194,304
    bf16_t* qb    = (bf16_t*)(wsb + 111149056);         //  4,194,304
    bf16_t* kb    = (bf16_t*)(wsb + 115343360);         //  4,194,304
    bf16_t* vb    = (bf16_t*)(wsb + 119537664);         //  4,194,304 (Vt [1024][2048])
    float*  cball = (float*) (wsb + 123731968);         //     20,480
    float*  e1t   = (float*) (wsb + 123752448);         //     65,536
    float*  e2t   = (float*) (wsb + 123817984);         //     65,536
    bf16_t* zpage = (bf16_t*)(wsb + 123883520);         //         64
    // aliases (stream-ordered reuse):
    bf16_t* fpwb = wcb;                 // wcb dead after conv GEMM
    bf16_t* wqb  = wcb + 5242880;       // wq||wk contiguous for merged QK GEMM
    bf16_t* wkb  = wqb + 1048576;
    bf16_t* wvb  = wkb + 1048576;
    bf16_t* woTb = wvb + 1048576;       // wo TRANSPOSED (bf16)
    bf16_t* gwb  = woTb + 1048576;
    bf16_t* qkb  = qb;                  // merged QK output [2048][2048] (qb+kb)
    float*  qkbias = e1t;               // e1t not needed until step 10
    bf16_t* ctxb = zb;                  // zb dead after QK/V projections
    bf16_t* wcomb = xb;                 // xb dead after conv GEMM: Wc = gat_w @ wo
    float*  bcomb = cball;              // cball dead after conv GEMM: folded bias
    bf16_t* hgtb = msb;                 // msb dead after fusion GEMM: hgT [1024][2048]

    const dim3 blk(256);

    // 1) feat conversion + conv weight reorder + bias gathers + zero page
    cvt_f32_bf16<<<dim3(2048), blk, 0, stream>>>(feat, xb, 524288);
    reorder_convw<<<dim3(20480), blk, 0, stream>>>(cw[0], cw[1], cw[2], cw[3], cw[4], wcb);
    gather_bias<<<dim3(28), blk, 0, stream>>>(cb[0], cb[1], cb[2], cb[3], cb[4],
                                              bq, bk, cball, qkbias, zpage);

    // 2) all 5 dilated convs, one MFMA launch -> msb (bf16, ld 5120)
    mfma_gemm<true, true><<<dim3(40, 16), blk, 0, stream>>>(
        xb, wcb, cball, msb, zpage, 1024, 1024, 1024, 5120, 0);

    // 3) weight conversions (aliases wcb -> after conv) + woT + folded bias
    cvt_multi<<<dim3(9216), blk, 0, stream>>>(fp_w, wq, wk, wv, gat_w,
                                              fpwb, wqb, wkb, wvb, gwb);
    transpose_w<<<dim3(32, 32), blk, 0, stream>>>(wo, woTb);
    fold_bias<<<dim3(256), blk, 0, stream>>>(gat_w, bo, gat_b, bcomb);

    // 3b) merged projection weight: Wc[d,i] = sum_o gat_w[d,o]*wo[o,i]  -> xb
    mfma_gemm<false, true, false, 64><<<dim3(8, 16), blk, 0, stream>>>(
        gwb, woTb, nullptr, wcomb, zpage, 1024, 1024, 1024, 1024, 0);

    // 4) fusion projection -> zf (fp32); 64-row tiles -> 256 blocks
    mfma_gemm<false, false, false, 64><<<dim3(8, 32), blk, 0, stream>>>(
        msb, fpwb, fp_b, zf, zpage, 5120, 5120, 5120, 1024, 0);

    // 5) LN + GELU -> zf (fp32) and zb (bf16)
    ln_gelu<<<dim3(2048), blk, 0, stream>>>(zf, zb, ln_g, ln_b);

    // 6) merged Q+K projection -> qkb [2048][2048] (NR=64: 512 blocks, 2/CU);
    //    V operand-swapped -> Vt
    mfma_gemm<false, true, false, 64><<<dim3(16, 32), blk, 0, stream>>>(
        zb, wqb, qkbias, qkb, zpage, 1024, 1024, 1024, 2048, 0);
    mfma_gemm<false, true, true, 64><<<dim3(16, 16), blk, 0, stream>>>(
        wvb, zb, bv, vb, zpage, 1024, 1024, 1024, 2048, 0);

    // 7) MFMA flash attention -> ctxb (bf16)
    attn_mfma<<<dim3(2, 16, 8), blk, 0, stream>>>(qkb, qkb + 1024, vb, ctxb);

    // 8) merged (wo+gat) projection, TRANSPOSED out:
    //    hgT[d][tok] = bc[d] + sum_c Wc[d,c]*ctx[tok,c]   -> msb (bf16, ld 2048)
    mfma_gemm<false, true, true, 64><<<dim3(16, 16), blk, 0, stream>>>(
        wcomb, ctxb, bcomb, hgtb, zpage, 1024, 1024, 1024, 2048, 0);

    // 9) GAT: logits from hgT, fused softmax-aggregate (MFMA)
    gat_e<<<dim3(64), blk, 0, stream>>>(hgtb, ga1, ga2, e1t, e2t);
    gat_agg_mfma<<<dim3(32, 8), blk, 0, stream>>>(hgtb, e1t, e2t, feat, outp);
}

// Round 7
// 641.131 us; speedup vs baseline: 1.2977x; 1.0273x over previous
//
#include <hip/hip_runtime.h>
#include <hip/hip_bf16.h>

typedef __bf16 bf16_t;
typedef bf16_t bf16x8 __attribute__((ext_vector_type(8)));
typedef bf16_t bf16x4v __attribute__((ext_vector_type(4)));
typedef float f32x4 __attribute__((ext_vector_type(4)));

// async 16B global->LDS (direct, no VGPR round trip)
__device__ __forceinline__ void gll16(const bf16_t* g, bf16_t* l) {
    __builtin_amdgcn_global_load_lds(
        (const __attribute__((address_space(1))) unsigned int*)g,
        (__attribute__((address_space(3))) unsigned int*)l, 16, 0, 0);
}

// ---------------------------------------------------------------------------
// prep1: conv-weight reorder (LDS-staged, coalesced) + feat fp32->bf16 +
// bias gathers + zero page.  One launch, grid 7196.
//   bid <  5120 : reorder one (i,o) row: (O,C,7) fp32 -> planes [(i*7+kk)][o][c]
//   bid <  7168 : feat -> xb (bf16)
//   bid == 7168+: conv biases -> cball, bq||bk -> qkbias, zero page
// ---------------------------------------------------------------------------
__global__ __launch_bounds__(256)
void prep1(const float* w0, const float* w1, const float* w2, const float* w3,
           const float* w4, const float* feat,
           const float* b0, const float* b1, const float* b2, const float* b3,
           const float* b4, const float* bq, const float* bk,
           bf16_t* __restrict__ wout, bf16_t* __restrict__ xb,
           float* __restrict__ cball, float* __restrict__ qkbias,
           bf16_t* __restrict__ zp)
{
    __shared__ __align__(16) float s[7168];
    const int bid = blockIdx.x, t = threadIdx.x;
    if (bid < 5120) {
        int i = bid >> 10, o = bid & 1023;
        const float* ws[5] = {w0, w1, w2, w3, w4};
        const float* src = ws[i] + (size_t)o * 7168;
        #pragma unroll
        for (int r = 0; r < 7; r++)
            ((float4*)s)[r * 256 + t] = ((const float4*)src)[r * 256 + t];
        __syncthreads();
        const int c4 = t * 4;
        #pragma unroll
        for (int kk = 0; kk < 7; kk++) {
            bf16x4v v = { (bf16_t)s[c4 * 7 + kk], (bf16_t)s[(c4 + 1) * 7 + kk],
                          (bf16_t)s[(c4 + 2) * 7 + kk], (bf16_t)s[(c4 + 3) * 7 + kk] };
            *(bf16x4v*)&wout[((size_t)(i * 7 + kk) << 20) + (o << 10) + c4] = v;
        }
    } else if (bid < 7168) {
        int i = (bid - 5120) * 256 + t;          // < 524288
        float4 v = ((const float4*)feat)[i];
        bf16x4v o4 = { (bf16_t)v.x, (bf16_t)v.y, (bf16_t)v.z, (bf16_t)v.w };
        *(bf16x4v*)&xb[i * 4] = o4;
    } else {
        int idx = (bid - 7168) * 256 + t;        // < 7168
        if (bid == 7168 && t < 32) zp[t] = (bf16_t)0.0f;
        if (idx < 5120) {
            const float* bs[5] = {b0, b1, b2, b3, b4};
            cball[idx] = bs[idx >> 10][idx & 1023];
        } else {
            int j = idx - 5120;                  // < 2048
            qkbias[j] = (j < 1024) ? bq[j] : bk[j - 1024];
        }
    }
}

// ---------------------------------------------------------------------------
// prep2: fp32->bf16 for fp_w/wq/wk/wv/gat_w + wo transpose (bf16) + folded
// bias bc = gat_b + gat_w@bo.  One launch, grid 10496.
// ---------------------------------------------------------------------------
__global__ __launch_bounds__(256)
void prep2(const float* __restrict__ fpw, const float* __restrict__ wq,
           const float* __restrict__ wk, const float* __restrict__ wv,
           const float* __restrict__ gw, const float* __restrict__ wo,
           const float* __restrict__ bo, const float* __restrict__ gb,
           bf16_t* __restrict__ fpwb, bf16_t* __restrict__ wqb,
           bf16_t* __restrict__ wkb, bf16_t* __restrict__ wvb,
           bf16_t* __restrict__ gwb, bf16_t* __restrict__ woTb,
           float* __restrict__ bc)
{
    __shared__ float tile[32][33];
    const int bid = blockIdx.x, t = threadIdx.x;
    if (bid < 9216) {
        int id = bid * 256 + t;                  // < 2359296
        const float* src; bf16_t* dst; int off;
        if (id < 1310720) { src = fpw; dst = fpwb; off = id; }
        else {
            int id3 = id - 1310720;
            int w = id3 >> 18; off = id3 & 262143;
            const float* ss[4] = {wq, wk, wv, gw};
            bf16_t* dd[4] = {wqb, wkb, wvb, gwb};
            src = ss[w]; dst = dd[w];
        }
        float4 v = ((const float4*)src)[off];
        bf16x4v o = { (bf16_t)v.x, (bf16_t)v.y, (bf16_t)v.z, (bf16_t)v.w };
        *(bf16x4v*)&dst[off * 4] = o;
    } else if (bid < 10240) {
        int idx = bid - 9216;                    // < 1024 tiles
        int j0 = (idx & 31) * 32, c0 = (idx >> 5) * 32;
        {
            int jl = t >> 3, cl = (t & 7) * 4;
            float4 v = *(const float4*)(wo + (size_t)(j0 + jl) * 1024 + c0 + cl);
            tile[jl][cl] = v.x; tile[jl][cl + 1] = v.y;
            tile[jl][cl + 2] = v.z; tile[jl][cl + 3] = v.w;
        }
        __syncthreads();
        {
            int cl = t >> 3, jl = (t & 7) * 4;
            bf16x4v o = { (bf16_t)tile[jl][cl], (bf16_t)tile[jl + 1][cl],
                          (bf16_t)tile[jl + 2][cl], (bf16_t)tile[jl + 3][cl] };
            *(bf16x4v*)&woTb[(size_t)(c0 + cl) * 1024 + j0 + jl] = o;
        }
    } else {
        int wave = t >> 6, lane = t & 63;
        int d = (bid - 10240) * 4 + wave;        // < 1024
        const float* row = gw + (size_t)d * 1024;
        float ssum = 0.f;
        #pragma unroll
        for (int k = lane * 4; k < 1024; k += 256) {
            float4 x = *(const float4*)&row[k];
            float4 a = *(const float4*)&bo[k];
            ssum += x.x * a.x + x.y * a.y + x.z * a.z + x.w * a.w;
        }
        ssum += __shfl_xor(ssum, 1);  ssum += __shfl_xor(ssum, 2);
        ssum += __shfl_xor(ssum, 4);  ssum += __shfl_xor(ssum, 8);
        ssum += __shfl_xor(ssum, 16); ssum += __shfl_xor(ssum, 32);
        if (lane == 0) bc[d] = gb[d] + ssum;
    }
}

// ---------------------------------------------------------------------------
// Generic bf16 MFMA NT GEMM body: out[n,m] = sum_k A[n,k]*B[m,k] + bias.
// Tile NRx128, BK=32, 4 waves, depth-2 / 3-buffer pipeline, counted vmcnt
// (4 for NR=128, 3 for NR=64; depth-3 measured WORSE: 64KB LDS halves
// occupancy, r4).  Running source pointers (init once, += 32 per stage).
// LDS slot swizzle: 16B slot ^= (row>>1)&3 on source column and read slot.
// flags: bit0 = bf16 out, bit1 = bias indexed by row (transposed-out GEMM).
// ---------------------------------------------------------------------------
struct GemmP {
    const bf16_t* A; const bf16_t* Bw; const float* bias; void* outv;
    int Kd, lda, ldb, ldo, flags;
};

template<int NR>
__device__ __forceinline__ void gemm_body(char* smemraw, const GemmP P,
                                          int bx, int by)
{
    constexpr int FN = NR / 32, NA = NR / 64;
    auto As = (bf16_t(*)[NR * 32])smemraw;
    auto Bs = (bf16_t(*)[128 * 32])(smemraw + 3 * NR * 32 * 2);
    const int t = threadIdx.x, lane = t & 63, wave = t >> 6;
    const int wn = (wave & 1) * (NR / 2), wm = (wave >> 1) * 64;
    const int q = lane >> 4, lr = lane & 15;
    const int m0 = bx * 128, n0 = by * NR;
    const int srow = lane >> 2, sseg = lane & 3;
    const int sw_seg = sseg ^ ((srow >> 1) & 3);
    const int slotq = (q ^ ((lr >> 1) & 3)) * 8;

    f32x4 acc[FN][4];
    #pragma unroll
    for (int a = 0; a < FN; a++)
        #pragma unroll
        for (int b = 0; b < 4; b++) acc[a][b] = (f32x4){0.f, 0.f, 0.f, 0.f};

    const bf16_t* aptr[NA]; const bf16_t* bptr[2];
    #pragma unroll
    for (int p = 0; p < NA; p++)
        aptr[p] = P.A + (size_t)(n0 + p * 64 + wave * 16 + srow) * P.lda + sw_seg * 8;
    #pragma unroll
    for (int p = 0; p < 2; p++)
        bptr[p] = P.Bw + (size_t)(m0 + p * 64 + wave * 16 + srow) * P.ldb + sw_seg * 8;

    const int T = P.Kd >> 5;
    auto do_stage = [&](int bi) {
        #pragma unroll
        for (int p = 0; p < NA; p++) {
            gll16(aptr[p], &As[bi][(p * 64 + wave * 16) * 32]);
            aptr[p] += 32;
        }
        #pragma unroll
        for (int p = 0; p < 2; p++) {
            gll16(bptr[p], &Bs[bi][(p * 64 + wave * 16) * 32]);
            bptr[p] += 32;
        }
    };
    do_stage(0);
    do_stage(1);

    int cur = 0;
    for (int s = 0; s < T; s++) {
        if (s + 1 < T) {
            if constexpr (NR == 128) asm volatile("s_waitcnt vmcnt(4)" ::: "memory");
            else                     asm volatile("s_waitcnt vmcnt(3)" ::: "memory");
        } else {
            asm volatile("s_waitcnt vmcnt(0)" ::: "memory");
        }
        __builtin_amdgcn_s_barrier();
        __builtin_amdgcn_sched_barrier(0);

        bf16x8 af[FN], bfv[4];
        #pragma unroll
        for (int f = 0; f < FN; f++)
            af[f] = *(bf16x8*)&As[cur][(wn + f * 16 + lr) * 32 + slotq];
        #pragma unroll
        for (int f = 0; f < 4; f++)
            bfv[f] = *(bf16x8*)&Bs[cur][(wm + f * 16 + lr) * 32 + slotq];

        int nb = cur + 2; if (nb >= 3) nb -= 3;
        if (s + 2 < T) do_stage(nb);

        __builtin_amdgcn_s_setprio(1);
        #pragma unroll
        for (int fn = 0; fn < FN; fn++)
            #pragma unroll
            for (int fm = 0; fm < 4; fm++)
                acc[fn][fm] = __builtin_amdgcn_mfma_f32_16x16x32_bf16(
                    af[fn], bfv[fm], acc[fn][fm], 0, 0, 0);
        __builtin_amdgcn_s_setprio(0);
        cur++; if (cur == 3) cur = 0;
    }

    const bool obf = P.flags & 1, brow = P.flags & 2;
    #pragma unroll
    for (int fn = 0; fn < FN; fn++) {
        #pragma unroll
        for (int r = 0; r < 4; r++) {
            int n = n0 + wn + fn * 16 + q * 4 + r;
            #pragma unroll
            for (int fm = 0; fm < 4; fm++) {
                int m = m0 + wm + fm * 16 + lr;
                float v = acc[fn][fm][r];
                if (P.bias) v += P.bias[brow ? n : m];
                if (obf) ((bf16_t*)P.outv)[(size_t)n * P.ldo + m] = (bf16_t)v;
                else     ((float*)P.outv)[(size_t)n * P.ldo + m] = v;
            }
        }
    }
}

template<int NR>
__global__ __launch_bounds__(256)
void mfma_gemm_one(GemmP P)
{
    __shared__ __align__(16) char smem[3 * NR * 32 * 2 + 3 * 128 * 32 * 2];
    gemm_body<NR>(smem, P, blockIdx.x, blockIdx.y);
}

// Two independent GEMMs in one launch (y < ysplit -> P0, else P1).
template<int NR>
__global__ __launch_bounds__(256)
void mfma_gemm_dual(GemmP P0, GemmP P1, int ysplit)
{
    __shared__ __align__(16) char smem[3 * NR * 32 * 2 + 3 * 128 * 32 * 2];
    if ((int)blockIdx.y < ysplit)
        gemm_body<NR>(smem, P0, blockIdx.x, blockIdx.y);
    else
        gemm_body<NR>(smem, P1, blockIdx.x, blockIdx.y - ysplit);
}

// ---------------------------------------------------------------------------
// Conv GEMM: all 5 dilated convs.  Grid x = conv_i*8 + m-tile (XCD = m-tile),
// y = n-tile.  128x128 tile, 7-tap loop; running pointers recomputed only at
// tap boundaries (per-lane OOB/zpage resolved into ptr + inc(32|0) once/tap).
// ---------------------------------------------------------------------------
__global__ __launch_bounds__(256)
void mfma_gemm_conv(const bf16_t* __restrict__ A, const bf16_t* __restrict__ Bw,
                    const float* __restrict__ bias, bf16_t* __restrict__ out,
                    const bf16_t* __restrict__ zp)
{
    __shared__ __align__(16) bf16_t As[3][128 * 32];
    __shared__ __align__(16) bf16_t Bs[3][128 * 32];
    const int t = threadIdx.x, lane = t & 63, wave = t >> 6;
    const int wn = (wave & 1) * 64, wm = (wave >> 1) * 64;
    const int q = lane >> 4, lr = lane & 15;
    const int mt = blockIdx.x & 7, conv_i = blockIdx.x >> 3;
    const int m0 = mt * 128, n0 = blockIdx.y * 128;
    const int srow = lane >> 2, sseg = lane & 3;
    const int sw_seg = sseg ^ ((srow >> 1) & 3);
    const int slotq = (q ^ ((lr >> 1) & 3)) * 8;

    f32x4 acc[4][4];
    #pragma unroll
    for (int a = 0; a < 4; a++)
        #pragma unroll
        for (int b = 0; b < 4; b++) acc[a][b] = (f32x4){0.f, 0.f, 0.f, 0.f};

    const bf16_t* aptr[2]; int ainc[2];
    const bf16_t* bptr[2];
    int s_tap = 0, s_k0 = 0;

    auto tap_init = [&]() {
        const bf16_t* Bp = Bw + ((size_t)(conv_i * 7 + s_tap) << 20);
        const int shift = (s_tap - 3) << conv_i;
        #pragma unroll
        for (int p = 0; p < 2; p++) {
            const int slab = p * 64 + wave * 16;
            const int slabN = n0 + slab;                 // wave-uniform
            const int inSeg = slabN & 255;
            if (inSeg + shift >= 0 && inSeg + shift <= 240) {
                aptr[p] = A + (size_t)(slabN + srow + shift) * 1024 + sw_seg * 8;
                ainc[p] = 32;
            } else {
                int n = slabN + srow;
                int tg = (n & 255) + shift;
                bool ok = (unsigned)tg < 256u;
                aptr[p] = ok ? A + (size_t)((n & ~255) + tg) * 1024 + sw_seg * 8
                             : zp + sseg * 8;
                ainc[p] = ok ? 32 : 0;
            }
            bptr[p] = Bp + (size_t)(m0 + slab + srow) * 1024 + sw_seg * 8;
        }
    };
    auto do_stage = [&](int bi) {
        #pragma unroll
        for (int p = 0; p < 2; p++) {
            const int slab = p * 64 + wave * 16;
            gll16(aptr[p], &As[bi][slab * 32]);
            gll16(bptr[p], &Bs[bi][slab * 32]);
        }
        s_k0 += 32;
        if (s_k0 == 1024) {
            s_k0 = 0; s_tap++;
            if (s_tap < 7) tap_init();
        } else {
            #pragma unroll
            for (int p = 0; p < 2; p++) { aptr[p] += ainc[p]; bptr[p] += 32; }
        }
    };

    tap_init();
    do_stage(0);
    do_stage(1);

    const int T = 224;                                   // 7 taps x 32 K-steps
    int cur = 0;
    for (int s = 0; s < T; s++) {
        if (s + 1 < T) asm volatile("s_waitcnt vmcnt(4)" ::: "memory");
        else           asm volatile("s_waitcnt vmcnt(0)" ::: "memory");
        __builtin_amdgcn_s_barrier();
        __builtin_amdgcn_sched_barrier(0);

        bf16x8 af[4], bfv[4];
        #pragma unroll
        for (int f = 0; f < 4; f++) {
            af[f]  = *(bf16x8*)&As[cur][(wn + f * 16 + lr) * 32 + slotq];
            bfv[f] = *(bf16x8*)&Bs[cur][(wm + f * 16 + lr) * 32 + slotq];
        }
        int nb = cur + 2; if (nb >= 3) nb -= 3;
        if (s + 2 < T) do_stage(nb);

        __builtin_amdgcn_s_setprio(1);
        #pragma unroll
        for (int fn = 0; fn < 4; fn++)
            #pragma unroll
            for (int fm = 0; fm < 4; fm++)
                acc[fn][fm] = __builtin_amdgcn_mfma_f32_16x16x32_bf16(
                    af[fn], bfv[fm], acc[fn][fm], 0, 0, 0);
        __builtin_amdgcn_s_setprio(0);
        cur++; if (cur == 3) cur = 0;
    }

    const int oc0 = conv_i << 10;
    #pragma unroll
    for (int fn = 0; fn < 4; fn++) {
        #pragma unroll
        for (int r = 0; r < 4; r++) {
            int n = n0 + wn + fn * 16 + q * 4 + r;
            #pragma unroll
            for (int fm = 0; fm < 4; fm++) {
                int m = m0 + wm + fm * 16 + lr;
                out[(size_t)n * 5120 + oc0 + m] = (bf16_t)(acc[fn][fm][r] + bias[oc0 + m]);
            }
        }
    }
}

// ---------------------------------------------------------------------------
// LayerNorm (eps 1e-5) + exact GELU, in place on z (fp32) + bf16 copy zb.
// ---------------------------------------------------------------------------
__global__ __launch_bounds__(256)
void ln_gelu(float* __restrict__ z, bf16_t* __restrict__ zb,
             const float* __restrict__ g, const float* __restrict__ b)
{
    __shared__ float r1[256], r2[256];
    const int n = blockIdx.x, t = threadIdx.x;
    float* row = z + (size_t)n * 1024;
    float x[4], s = 0.f, s2 = 0.f;
    #pragma unroll
    for (int u = 0; u < 4; u++) {
        x[u] = row[t + u * 256];
        s += x[u]; s2 += x[u] * x[u];
    }
    r1[t] = s; r2[t] = s2;
    __syncthreads();
    for (int off = 128; off > 0; off >>= 1) {
        if (t < off) { r1[t] += r1[t + off]; r2[t] += r2[t + off]; }
        __syncthreads();
    }
    const float mu  = r1[0] * (1.0f / 1024.0f);
    const float var = r2[0] * (1.0f / 1024.0f) - mu * mu;
    const float rstd = rsqrtf(var + 1e-5f);
    #pragma unroll
    for (int u = 0; u < 4; u++) {
        int c = t + u * 256;
        float y = (x[u] - mu) * rstd * g[c] + b[c];
        float gv = 0.5f * y * (1.0f + erff(y * 0.70710678118654752f));
        row[c] = gv;
        zb[(size_t)n * 1024 + c] = (bf16_t)gv;
    }
}

// ---------------------------------------------------------------------------
// MFMA flash attention.
// Grid (2 i-tiles x 16 heads x 8 batch) = 256 blocks, 4 waves.
// q,k: interleaved QK buffer [2048][2048] bf16; vt: [1024 dims][2048 tokens];
// ctx: [2048][1024].  LDS XOR-swizzled (16B slot ^= row&7).
// ---------------------------------------------------------------------------
__global__ __launch_bounds__(256)
void attn_mfma(const bf16_t* __restrict__ qg, const bf16_t* __restrict__ kg,
               const bf16_t* __restrict__ vt, bf16_t* __restrict__ ctx)
{
    const int it = blockIdx.x, h = blockIdx.y, bb = blockIdx.z;
    const int t = threadIdx.x, lane = t & 63, wave = t >> 6;
    const int q4 = lane >> 4, lr = lane & 15;
    const size_t qkbase = (size_t)bb * 256 * 2048 + (size_t)h * 64;

    __shared__ __align__(16) bf16_t Qs[4][32 * 64];
    __shared__ __align__(16) bf16_t Ks[64 * 64];
    __shared__ __align__(16) bf16_t Vs[64 * 64];
    __shared__ __align__(16) bf16_t Ps[4][32 * 64];

    {
        const int itbase = it * 128;
        #pragma unroll
        for (int rep = 0; rep < 4; rep++) {
            int idx = rep * 256 + t;
            int rl = idx >> 3, seg = idx & 7;
            bf16x8 v = *(const bf16x8*)&qg[qkbase + (size_t)(itbase + rl) * 2048 + seg * 8];
            *(bf16x8*)&Qs[rl >> 5][(rl & 31) * 64 + ((seg ^ (rl & 7)) << 3)] = v;
        }
    }

    f32x4 o[2][4];
    float mrow[2][4], lrow[2][4];
    #pragma unroll
    for (int fn = 0; fn < 2; fn++)
        #pragma unroll
        for (int x = 0; x < 4; x++) {
            o[fn][x] = (f32x4){0.f, 0.f, 0.f, 0.f};
            mrow[fn][x] = -1e30f; lrow[fn][x] = 0.f;
        }

    for (int j0 = 0; j0 < 256; j0 += 64) {
        __syncthreads();
        #pragma unroll
        for (int rep = 0; rep < 2; rep++) {
            int idx = rep * 256 + t;
            int rl = idx >> 3, seg = idx & 7;
            bf16x8 kv = *(const bf16x8*)&kg[qkbase + (size_t)(j0 + rl) * 2048 + seg * 8];
            *(bf16x8*)&Ks[rl * 64 + ((seg ^ (rl & 7)) << 3)] = kv;
            bf16x8 vv = *(const bf16x8*)&vt[(size_t)(h * 64 + rl) * 2048 + bb * 256 + j0 + seg * 8];
            *(bf16x8*)&Vs[rl * 64 + ((seg ^ (rl & 7)) << 3)] = vv;
        }
        __syncthreads();

        f32x4 s[2][4];
        #pragma unroll
        for (int fn = 0; fn < 2; fn++)
            #pragma unroll
            for (int fm = 0; fm < 4; fm++) s[fn][fm] = (f32x4){0.f, 0.f, 0.f, 0.f};
        #pragma unroll
        for (int kk = 0; kk < 2; kk++) {
            bf16x8 aq[2], bk[4];
            #pragma unroll
            for (int fn = 0; fn < 2; fn++) {
                int row = fn * 16 + lr;
                aq[fn] = *(bf16x8*)&Qs[wave][row * 64 + (((kk * 4 + q4) ^ (row & 7)) << 3)];
            }
            #pragma unroll
            for (int fm = 0; fm < 4; fm++) {
                int row = fm * 16 + lr;
                bk[fm] = *(bf16x8*)&Ks[row * 64 + (((kk * 4 + q4) ^ (row & 7)) << 3)];
            }
            #pragma unroll
            for (int fn = 0; fn < 2; fn++)
                #pragma unroll
                for (int fm = 0; fm < 4; fm++)
                    s[fn][fm] = __builtin_amdgcn_mfma_f32_16x16x32_bf16(
                        aq[fn], bk[fm], s[fn][fm], 0, 0, 0);
        }

        #pragma unroll
        for (int fn = 0; fn < 2; fn++) {
            #pragma unroll
            for (int r = 0; r < 4; r++) {
                float sv[4];
                #pragma unroll
                for (int fm = 0; fm < 4; fm++) sv[fm] = s[fn][fm][r] * 0.125f;
                float rm = fmaxf(fmaxf(sv[0], sv[1]), fmaxf(sv[2], sv[3]));
                rm = fmaxf(rm, __shfl_xor(rm, 1));
                rm = fmaxf(rm, __shfl_xor(rm, 2));
                rm = fmaxf(rm, __shfl_xor(rm, 4));
                rm = fmaxf(rm, __shfl_xor(rm, 8));
                float mold = mrow[fn][r];
                float mnew = fmaxf(mold, rm);
                float scl = __expf(mold - mnew);
                mrow[fn][r] = mnew;
                int prow = fn * 16 + q4 * 4 + r;
                float psum = 0.f;
                #pragma unroll
                for (int fm = 0; fm < 4; fm++) {
                    float p = __expf(sv[fm] - mnew);
                    psum += p;
                    int col = fm * 16 + lr;
                    Ps[wave][prow * 64 + (col ^ ((prow & 7) << 3))] = (bf16_t)p;
                }
                psum += __shfl_xor(psum, 1);
                psum += __shfl_xor(psum, 2);
                psum += __shfl_xor(psum, 4);
                psum += __shfl_xor(psum, 8);
                lrow[fn][r] = lrow[fn][r] * scl + psum;
                #pragma unroll
                for (int fd = 0; fd < 4; fd++) o[fn][fd][r] *= scl;
            }
        }

        #pragma unroll
        for (int kk = 0; kk < 2; kk++) {
            bf16x8 ap[2], bvf[4];
            #pragma unroll
            for (int fn = 0; fn < 2; fn++) {
                int row = fn * 16 + lr;
                ap[fn] = *(bf16x8*)&Ps[wave][row * 64 + (((kk * 4 + q4) ^ (row & 7)) << 3)];
            }
            #pragma unroll
            for (int fd = 0; fd < 4; fd++) {
                int row = fd * 16 + lr;
                bvf[fd] = *(bf16x8*)&Vs[row * 64 + (((kk * 4 + q4) ^ (row & 7)) << 3)];
            }
            #pragma unroll
            for (int fn = 0; fn < 2; fn++)
                #pragma unroll
                for (int fd = 0; fd < 4; fd++)
                    o[fn][fd] = __builtin_amdgcn_mfma_f32_16x16x32_bf16(
                        ap[fn], bvf[fd], o[fn][fd], 0, 0, 0);
        }
    }

    const int i0 = it * 128 + wave * 32;
    #pragma unroll
    for (int fn = 0; fn < 2; fn++) {
        #pragma unroll
        for (int r = 0; r < 4; r++) {
            float inv = 1.0f / lrow[fn][r];
            int row = i0 + fn * 16 + q4 * 4 + r;
            #pragma unroll
            for (int fd = 0; fd < 4; fd++) {
                int col = h * 64 + fd * 16 + lr;
                ctx[(size_t)bb * 262144 + (size_t)row * 1024 + col] =
                    (bf16_t)(o[fn][fd][r] * inv);
            }
        }
    }
}

// ---------------------------------------------------------------------------
// GAT logits from hgT (bf16, [1024][2048]): e1t[h][n] = sum_d hgT[h*128+d][n]*a1[d].
// ---------------------------------------------------------------------------
__global__ __launch_bounds__(256)
void gat_e(const bf16_t* __restrict__ hgT, const float* __restrict__ a1,
           const float* __restrict__ a2, float* __restrict__ e1t,
           float* __restrict__ e2t)
{
    int id = blockIdx.x * 256 + threadIdx.x;  // < 16384
    int h = id >> 11, n = id & 2047;
    const bf16_t* base = hgT + (size_t)(h * 128) * 2048 + n;
    float s1 = 0.f, s2 = 0.f;
    #pragma unroll 4
    for (int d = 0; d < 128; d++) {
        float x = (float)base[(size_t)d * 2048];
        s1 += x * a1[d];
        s2 += x * a2[d];
    }
    e1t[id] = s1; e2t[id] = s2;
}

// ---------------------------------------------------------------------------
// Fused GAT softmax-aggregate via MFMA.  Grid (32, 8) x 256.
// Single pass: m_i = leaky(e1_i + max_j e2_j) (leaky monotone -> exact);
// denominator via per-thread register partials + 16-lane shuffle reduce.
// ---------------------------------------------------------------------------
__global__ __launch_bounds__(256)
void gat_agg_mfma(const bf16_t* __restrict__ hgT, const float* __restrict__ e1t,
                  const float* __restrict__ e2t, const float* __restrict__ feat,
                  float* __restrict__ outp)
{
    const int it = blockIdx.x, h = blockIdx.y;
    const int i0 = it * 64;
    __shared__ float e2s[2048];
    __shared__ float e1s[64], mS[64], lSinv[64];
    __shared__ float wmax[4];
    __shared__ __align__(16) bf16_t Ps[64 * 136];
    __shared__ __align__(16) bf16_t Hs[128 * 136];
    const int t = threadIdx.x;
    const int lane = t & 63, wave = t >> 6;
    const int q = lane >> 4, lr = lane & 15;
    const int wm = wave * 32;

    float lmax = -1e30f;
    for (int idx = t; idx < 2048; idx += 256) {
        float v = e2t[h * 2048 + idx];
        e2s[idx] = v;
        lmax = fmaxf(lmax, v);
    }
    if (t < 64) e1s[t] = e1t[h * 2048 + i0 + t];
    #pragma unroll
    for (int d = 1; d < 64; d <<= 1) lmax = fmaxf(lmax, __shfl_xor(lmax, d));
    if (lane == 0) wmax[wave] = lmax;
    __syncthreads();
    {
        float maxE2 = fmaxf(fmaxf(wmax[0], wmax[1]), fmaxf(wmax[2], wmax[3]));
        if (t < 64) {
            float x = e1s[t] + maxE2;
            mS[t] = (x >= 0.f) ? x : 0.2f * x;
        }
    }
    __syncthreads();

    f32x4 acc[4][2];
    #pragma unroll
    for (int a = 0; a < 4; a++)
        #pragma unroll
        for (int b = 0; b < 2; b++) acc[a][b] = (f32x4){0.f, 0.f, 0.f, 0.f};
    float psum[4] = {0.f, 0.f, 0.f, 0.f};

    for (int j0 = 0; j0 < 2048; j0 += 128) {
        for (int idx = t; idx < 2048; idx += 256) {
            int d = idx >> 4, seg = idx & 15;
            *(bf16x8*)&Hs[d * 136 + seg * 8] =
                *(const bf16x8*)&hgT[(size_t)(h * 128 + d) * 2048 + j0 + seg * 8];
        }
        #pragma unroll
        for (int rep = 0; rep < 4; rep++) {
            int idx = rep * 256 + t;
            int i = idx >> 4, jg = idx & 15;
            float ei = e1s[i], mi = mS[i];
            bf16x8 pv;
            #pragma unroll
            for (int u = 0; u < 8; u++) {
                float x = ei + e2s[j0 + jg * 8 + u];
                x = (x >= 0.f) ? x : 0.2f * x;
                float p = __expf(x - mi);
                psum[rep] += p;
                pv[u] = (bf16_t)p;
            }
            *(bf16x8*)&Ps[i * 136 + jg * 8] = pv;
        }
        __syncthreads();
        #pragma unroll
        for (int kb = 0; kb < 4; kb++) {
            bf16x8 af[4], bf2[2];
            #pragma unroll
            for (int fn = 0; fn < 4; fn++)
                af[fn] = *(bf16x8*)&Ps[(fn * 16 + lr) * 136 + kb * 32 + q * 8];
            #pragma unroll
            for (int fm = 0; fm < 2; fm++)
                bf2[fm] = *(bf16x8*)&Hs[(wm + fm * 16 + lr) * 136 + kb * 32 + q * 8];
            #pragma unroll
            for (int fn = 0; fn < 4; fn++)
                #pragma unroll
                for (int fm = 0; fm < 2; fm++)
                    acc[fn][fm] = __builtin_amdgcn_mfma_f32_16x16x32_bf16(
                        af[fn], bf2[fm], acc[fn][fm], 0, 0, 0);
        }
        __syncthreads();
    }

    #pragma unroll
    for (int rep = 0; rep < 4; rep++) {
        float v = psum[rep];
        v += __shfl_xor(v, 1);
        v += __shfl_xor(v, 2);
        v += __shfl_xor(v, 4);
        v += __shfl_xor(v, 8);
        if ((t & 15) == 0) lSinv[rep * 16 + (t >> 4)] = 1.0f / v;
    }
    __syncthreads();

    #pragma unroll
    for (int fn = 0; fn < 4; fn++) {
        #pragma unroll
        for (int r = 0; r < 4; r++) {
            int il = fn * 16 + q * 4 + r;
            int i = i0 + il;
            float inv = lSinv[il];
            #pragma unroll
            for (int fm = 0; fm < 2; fm++) {
                int col = h * 128 + wm + fm * 16 + lr;
                float v = acc[fn][fm][r] * inv;
                v = (v > 0.f) ? v : (expf(v) - 1.0f);
                size_t off = (size_t)i * 1024 + col;
                outp[off] = v + feat[off];
            }
        }
    }
}

// ---------------------------------------------------------------------------
extern "C" void kernel_launch(void* const* d_in, const int* in_sizes, int n_in,
                              void* d_out, int out_size, void* d_ws, size_t ws_size,
                              hipStream_t stream)
{
    const float* feat = (const float*)d_in[0];
    const float *cw[5], *cb[5];
    if (in_sizes[2] == 1024) {
        for (int i = 0; i < 5; i++) { cw[i] = (const float*)d_in[1 + 2*i]; cb[i] = (const float*)d_in[2 + 2*i]; }
    } else {
        for (int i = 0; i < 5; i++) { cw[i] = (const float*)d_in[1 + i];   cb[i] = (const float*)d_in[6 + i]; }
    }
    const float* fp_w = (const float*)d_in[11];
    const float* fp_b = (const float*)d_in[12];
    const float* ln_g = (const float*)d_in[13];
    const float* ln_b = (const float*)d_in[14];
    const float* wq = (const float*)d_in[15]; const float* bq = (const float*)d_in[16];
    const float* wk = (const float*)d_in[17]; const float* bk = (const float*)d_in[18];
    const float* wv = (const float*)d_in[19]; const float* bv = (const float*)d_in[20];
    const float* wo = (const float*)d_in[21]; const float* bo = (const float*)d_in[22];
    const float* gat_w = (const float*)d_in[23]; const float* gat_b = (const float*)d_in[24];
    const float* ga1 = (const float*)d_in[25]; const float* ga2 = (const float*)d_in[26];
    float* outp = (float*)d_out;

    // ---- workspace layout (~118 MiB) ----
    char* wsb = (char*)d_ws;
    bf16_t* xb    = (bf16_t*)(wsb);                     //  4,194,304
    bf16_t* msb   = (bf16_t*)(wsb + 4194304);           // 20,971,520
    bf16_t* wcb   = (bf16_t*)(wsb + 25165824);          // 73,400,320
    float*  zf    = (float*) (wsb + 98566144);          //  8,388,608
    bf16_t* zb    = (bf16_t*)(wsb + 106954752);         //  4,194,304
    bf16_t* qb    = (bf16_t*)(wsb + 111149056);         //  4,194,304
    bf16_t* kb    = (bf16_t*)(wsb + 115343360);         //  4,194,304
    bf16_t* vb    = (bf16_t*)(wsb + 119537664);         //  4,194,304 (Vt [1024][2048])
    float*  cball = (float*) (wsb + 123731968);         //     20,480
    float*  e1t   = (float*) (wsb + 123752448);         //     65,536
    float*  e2t   = (float*) (wsb + 123817984);         //     65,536
    bf16_t* zpage = (bf16_t*)(wsb + 123883520);         //         64
    // aliases (stream-ordered reuse):
    bf16_t* fpwb = wcb;                 // wcb dead after conv GEMM
    bf16_t* wqb  = wcb + 5242880;       // wq||wk contiguous for merged QK GEMM
    bf16_t* wkb  = wqb + 1048576;
    bf16_t* wvb  = wkb + 1048576;
    bf16_t* woTb = wvb + 1048576;       // wo TRANSPOSED (bf16)
    bf16_t* gwb  = woTb + 1048576;
    bf16_t* qkb  = qb;                  // merged QK output [2048][2048]
    float*  qkbias = e1t;               // e1t not needed until step 9
    bf16_t* ctxb = zb;                  // zb dead after QK/V projections
    bf16_t* wcomb = xb;                 // xb dead after conv GEMM: Wc = gat_w @ wo
    float*  bcomb = cball;              // cball dead after conv GEMM
    bf16_t* hgtb = msb;                 // msb dead after fusion GEMM: hgT [1024][2048]

    const dim3 blk(256);

    // 1) prep1: conv weight reorder + feat->bf16 + biases + zero page
    prep1<<<dim3(7196), blk, 0, stream>>>(cw[0], cw[1], cw[2], cw[3], cw[4], feat,
                                          cb[0], cb[1], cb[2], cb[3], cb[4], bq, bk,
                                          wcb, xb, cball, qkbias, zpage);

    // 2) all 5 dilated convs, one MFMA launch -> msb (bf16, ld 5120)
    mfma_gemm_conv<<<dim3(40, 16), blk, 0, stream>>>(xb, wcb, cball, msb, zpage);

    // 3) prep2: weight conversions (alias wcb) + woT + folded bias
    prep2<<<dim3(10496), blk, 0, stream>>>(fp_w, wq, wk, wv, gat_w, wo, bo, gat_b,
                                           fpwb, wqb, wkb, wvb, gwb, woTb, bcomb);

    // 4) fusion projection (fp32 out) || wcomb = gat_w@wo (bf16 out), one launch
    {
        GemmP pf  = { msb, fpwb, fp_b, zf,    5120, 5120, 5120, 1024, 0 };
        GemmP pwc = { gwb, woTb, nullptr, wcomb, 1024, 1024, 1024, 1024, 1 };
        mfma_gemm_dual<64><<<dim3(8, 48), blk, 0, stream>>>(pf, pwc, 32);
    }

    // 5) LN + GELU -> zf (fp32) and zb (bf16)
    ln_gelu<<<dim3(2048), blk, 0, stream>>>(zf, zb, ln_g, ln_b);

    // 6) merged Q+K projection || V operand-swapped -> Vt, one launch
    {
        GemmP pqk = { zb,  wqb, qkbias, qkb, 1024, 1024, 1024, 2048, 1 };
        GemmP pv  = { wvb, zb,  bv,     vb,  1024, 1024, 1024, 2048, 3 };
        mfma_gemm_dual<64><<<dim3(16, 48), blk, 0, stream>>>(pqk, pv, 32);
    }

    // 7) MFMA flash attention -> ctxb (bf16)
    attn_mfma<<<dim3(2, 16, 8), blk, 0, stream>>>(qkb, qkb + 1024, vb, ctxb);

    // 8) merged (wo+gat) projection, TRANSPOSED out -> hgT (bf16, ld 2048)
    {
        GemmP pg = { wcomb, ctxb, bcomb, hgtb, 1024, 1024, 1024, 2048, 3 };
        mfma_gemm_one<64><<<dim3(16, 16), blk, 0, stream>>>(pg);
    }

    // 9) GAT: logits from hgT, fused softmax-aggregate (MFMA)
    gat_e<<<dim3(64), blk, 0, stream>>>(hgtb, ga1, ga2, e1t, e2t);
    gat_agg_mfma<<<dim3(32, 8), blk, 0, stream>>>(hgtb, e1t, e2t, feat, outp);
}